// Round 6
// baseline (934.596 us; speedup 1.0000x reference)
//
#include <hip/hip_runtime.h>
#include <cstddef>

#define TPB 256

typedef __bf16 bf16x8 __attribute__((ext_vector_type(8)));
typedef float f32x4 __attribute__((ext_vector_type(4)));
typedef unsigned short u16x8 __attribute__((ext_vector_type(8)));

__device__ __forceinline__ unsigned short f2bf(float f) {
  unsigned u = __float_as_uint(f);
  unsigned r = (u + 0x7FFFu + ((u >> 16) & 1u)) >> 16;
  return (unsigned short)r;
}
__device__ __forceinline__ float bf2f(unsigned short h) {
  return __uint_as_float(((unsigned)h) << 16);
}

// ---------------- P0: merged conv weights -> bf16 hi/lo in [tap][oc][c] ----------------
__global__ __launch_bounds__(TPB) void prep_w(
    const float* __restrict__ w1, const float* __restrict__ b1,
    const float* __restrict__ w3, const float* __restrict__ b3,
    const float* __restrict__ w5, const float* __restrict__ b5,
    unsigned short* __restrict__ wh, unsigned short* __restrict__ wl,
    float* __restrict__ b_eff) {
  int i = blockIdx.x * TPB + threadIdx.x;  // i < 25*65536
  int tap = i >> 16;
  int oc = (i >> 8) & 255;
  int c = i & 255;
  int kh = tap / 5, kw = tap - kh * 5;
  size_t occ = (size_t)((oc << 8) | c);
  float v = w5[occ * 25 + tap];
  if (kh >= 1 && kh <= 3 && kw >= 1 && kw <= 3)
    v += w3[occ * 9 + (kh - 1) * 3 + (kw - 1)];
  if (tap == 12) v += w1[occ];
  unsigned short h = f2bf(v);
  wh[i] = h;
  wl[i] = f2bf(v - bf2f(h));
  if (i < 256) b_eff[i] = b1[i] + b3[i] + b5[i];
}

// ---------------- P1: fp32 [b][256][1024] -> bf16 hi/lo [b][1024][256] (NCHW->NHWC) ----------------
__global__ __launch_bounds__(TPB) void prep_x(
    const float* __restrict__ x, unsigned short* __restrict__ xh,
    unsigned short* __restrict__ xl) {
  int i = blockIdx.x * TPB + threadIdx.x;  // < 16*32*1024
  int b = i >> 15, cg = (i >> 10) & 31, pix = i & 1023;
  u16x8 h8, l8;
#pragma unroll
  for (int j = 0; j < 8; ++j) {
    float v = x[((size_t)(b * 256 + cg * 8 + j)) * 1024 + pix];
    unsigned short h = f2bf(v);
    h8[j] = h;
    l8[j] = f2bf(v - bf2f(h));
  }
  size_t o = ((size_t)(b * 1024 + pix)) * 256 + cg * 8;
  *(u16x8*)(xh + o) = h8;
  *(u16x8*)(xl + o) = l8;
}

// ---------------- P2: generic weight fp32 -> bf16 hi/lo ----------------
__global__ __launch_bounds__(TPB) void prep_wgt(
    const float* __restrict__ w, unsigned short* __restrict__ h,
    unsigned short* __restrict__ l, int n) {
  int i = blockIdx.x * TPB + threadIdx.x;
  if (i < n) {
    float v = w[i];
    unsigned short hh = f2bf(v);
    h[i] = hh;
    l[i] = f2bf(v - bf2f(hh));
  }
}

// ---------------- K1: fused 5x5 conv via bf16 MFMA implicit GEMM ----------------
// grid (8 row-tiles, 4 oc-tiles, 16 b), block 256 (4 waves).
// x tile in LDS: 288 sites (8 rows x 36 cols) x 128B rows (8x16B chunks: 4 hi + 4 lo),
// chunk XOR-swizzled by site&7 -> conflict-free b128 reads/writes per 16-lane phase.
// B (weights) read per-lane from global (L1/L2-resident), no per-tap barriers.
__global__ __launch_bounds__(TPB) void conv5_mfma(
    const unsigned short* __restrict__ xh, const unsigned short* __restrict__ xl,
    const unsigned short* __restrict__ wh, const unsigned short* __restrict__ wl,
    const float* __restrict__ b_eff, float* __restrict__ out) {
  __shared__ unsigned short xs[288 * 64];
  const int tid = threadIdx.x;
  const int h0 = blockIdx.x * 4;
  const int oc0 = blockIdx.y * 64;
  const int b = blockIdx.z;
  const int lane = tid & 63;
  const int wr = tid >> 6;  // wave -> output row h0+wr
  const int l15 = lane & 15, cg = lane >> 4;

  f32x4 acc[2][4];
#pragma unroll
  for (int mf = 0; mf < 2; ++mf)
#pragma unroll
    for (int nf = 0; nf < 4; ++nf)
#pragma unroll
      for (int r = 0; r < 4; ++r) acc[mf][nf][r] = 0.f;

  // B row bases (element idx into wh/wl), advance by c0 and tap
  int brow[4];
#pragma unroll
  for (int nf = 0; nf < 4; ++nf) brow[nf] = (oc0 + nf * 16 + l15) * 256 + cg * 8;

  for (int c0 = 0; c0 < 256; c0 += 32) {
    __syncthreads();
    // stage x halo tile: 2304 uint4 tasks (288 sites x 8 chunks)
#pragma unroll
    for (int it = 0; it < 9; ++it) {
      int e = tid + it * TPB;
      int site = e >> 3, ch = e & 7;
      int row = site / 36, col = site - row * 36;
      int ih = h0 + row - 2, iw = col - 2;
      uint4 v = {0u, 0u, 0u, 0u};
      if ((unsigned)ih < 32u && (unsigned)iw < 32u) {
        size_t g = ((size_t)(b * 1024 + ih * 32 + iw)) * 256 + c0 + (ch & 3) * 8;
        v = (ch < 4) ? *(const uint4*)(xh + g) : *(const uint4*)(xl + g);
      }
      int chs = ch ^ (site & 7);
      *(uint4*)(xs + site * 64 + chs * 8) = v;
    }
    __syncthreads();

#pragma unroll
    for (int kh = 0; kh < 5; ++kh) {
#pragma unroll
      for (int kw = 0; kw < 5; ++kw) {
        const int tap = kh * 5 + kw;
        // B frags from global (hi/lo)
        bf16x8 Bh[4], Bl[4];
#pragma unroll
        for (int nf = 0; nf < 4; ++nf) {
          size_t g = (size_t)tap * 65536 + c0 + brow[nf];
          Bh[nf] = *(const bf16x8*)(wh + g);
          Bl[nf] = *(const bf16x8*)(wl + g);
        }
        // A frags from LDS (swizzled)
        bf16x8 Ah[2], Al[2];
#pragma unroll
        for (int mf = 0; mf < 2; ++mf) {
          int asite = (wr + kh) * 36 + mf * 16 + l15 + kw;
          int aoff = asite * 64 + ((cg ^ (asite & 7)) * 8);
          Ah[mf] = *(const bf16x8*)(xs + aoff);
          Al[mf] = *(const bf16x8*)(xs + (aoff ^ 32));
        }
#pragma unroll
        for (int mf = 0; mf < 2; ++mf)
#pragma unroll
          for (int nf = 0; nf < 4; ++nf) {
            acc[mf][nf] = __builtin_amdgcn_mfma_f32_16x16x32_bf16(Ah[mf], Bh[nf], acc[mf][nf], 0, 0, 0);
            acc[mf][nf] = __builtin_amdgcn_mfma_f32_16x16x32_bf16(Ah[mf], Bl[nf], acc[mf][nf], 0, 0, 0);
            acc[mf][nf] = __builtin_amdgcn_mfma_f32_16x16x32_bf16(Al[mf], Bh[nf], acc[mf][nf], 0, 0, 0);
          }
      }
    }
  }

  // epilogue: D col(oc)=l15, row(pixel col)=cg*4+r
#pragma unroll
  for (int mf = 0; mf < 2; ++mf)
#pragma unroll
    for (int nf = 0; nf < 4; ++nf) {
      int oc = oc0 + nf * 16 + l15;
      float bv = b_eff[oc];
      size_t base = ((size_t)(b * 256 + oc)) * 1024 + (h0 + wr) * 32 + mf * 16 + cg * 4;
      float4 r;
      r.x = acc[mf][nf][0] + bv;
      r.y = acc[mf][nf][1] + bv;
      r.z = acc[mf][nf][2] + bv;
      r.w = acc[mf][nf][3] + bv;
      *(float4*)(out + base) = r;
    }
}

// ---------------- K2: per-(b,c) avg+max pool ----------------
__global__ __launch_bounds__(TPB) void pool_avgmax(
    const float* __restrict__ out, float* __restrict__ avg, float* __restrict__ mx) {
  int bc = blockIdx.x;
  int tid = threadIdx.x;
  const float4 v = ((const float4*)(out + (size_t)bc * 1024))[tid];
  float s = v.x + v.y + v.z + v.w;
  float m = fmaxf(fmaxf(v.x, v.y), fmaxf(v.z, v.w));
#pragma unroll
  for (int off = 1; off < 64; off <<= 1) {
    s += __shfl_xor(s, off);
    m = fmaxf(m, __shfl_xor(m, off));
  }
  __shared__ float ss[4], ms[4];
  if ((tid & 63) == 0) { ss[tid >> 6] = s; ms[tid >> 6] = m; }
  __syncthreads();
  if (tid == 0) {
    s = ss[0] + ss[1] + ss[2] + ss[3];
    m = fmaxf(fmaxf(ms[0], ms[1]), fmaxf(ms[2], ms[3]));
    avg[bc] = s * (1.f / 1024.f);
    mx[bc] = m;
  }
}

// ---------------- K3: channel-attention MLP ----------------
__global__ __launch_bounds__(TPB) void ca_mlp(
    const float* __restrict__ avg, const float* __restrict__ mx,
    const float* __restrict__ w1, const float* __restrict__ w2,
    float* __restrict__ ca) {
  int b = blockIdx.x;
  int t = threadIdx.x;
  __shared__ float av[256], mv[256], h[16];
  av[t] = avg[b * 256 + t];
  mv[t] = mx[b * 256 + t];
  __syncthreads();
  if (t < 16) {
    float ha = 0.f, hm = 0.f;
    for (int c = 0; c < 256; ++c) {
      float wv = w1[t * 256 + c];
      ha += wv * av[c];
      hm += wv * mv[c];
    }
    h[t] = fmaxf(ha, 0.f) + fmaxf(hm, 0.f);
  }
  __syncthreads();
  float s = 0.f;
#pragma unroll
  for (int j = 0; j < 16; ++j) s += w2[t * 16 + j] * h[j];
  ca[b * 256 + t] = 1.f / (1.f + __expf(-s));
}

// ---------------- K4: c = out * ca ----------------
__global__ __launch_bounds__(TPB) void mul_ca(
    const float* __restrict__ out, const float* __restrict__ ca,
    float* __restrict__ cbuf) {
  int i = blockIdx.x * TPB + threadIdx.x;
  float4 v = ((const float4*)out)[i];
  float g = ca[i >> 8];
  v.x *= g; v.y *= g; v.z *= g; v.w *= g;
  ((float4*)cbuf)[i] = v;
}

// ---------------- K5: spatial mean/max over channels ----------------
__global__ __launch_bounds__(TPB) void spatial_pool(
    const float* __restrict__ cbuf, float* __restrict__ sa_in) {
  int i = blockIdx.x * TPB + threadIdx.x;
  int b = i >> 10, pix = i & 1023;
  const float* p = cbuf + (size_t)b * 262144 + pix;
  float s = 0.f, m = -3.4e38f;
  for (int ch = 0; ch < 256; ++ch) {
    float v = p[(size_t)ch * 1024];
    s += v;
    m = fmaxf(m, v);
  }
  sa_in[b * 2048 + pix] = s * (1.f / 256.f);
  sa_in[b * 2048 + 1024 + pix] = m;
}

// ---------------- K6: 7x7 spatial-attn conv + sigmoid ----------------
__global__ __launch_bounds__(TPB) void sa_conv(
    const float* __restrict__ sa_in, const float* __restrict__ sw,
    float* __restrict__ sa) {
  int i = blockIdx.x * TPB + threadIdx.x;
  int b = i >> 10, pix = i & 1023;
  int h = pix >> 5, w = pix & 31;
  float s = 0.f;
#pragma unroll
  for (int ci = 0; ci < 2; ++ci)
    for (int kh = 0; kh < 7; ++kh) {
      int ih = h + kh - 3;
      if ((unsigned)ih >= 32u) continue;
#pragma unroll
      for (int kw = 0; kw < 7; ++kw) {
        int iw = w + kw - 3;
        if ((unsigned)iw >= 32u) continue;
        s += sa_in[b * 2048 + ci * 1024 + ih * 32 + iw] * sw[ci * 49 + kh * 7 + kw];
      }
    }
  sa[i] = 1.f / (1.f + __expf(-s));
}

// ---------------- K7: cbam = c * sa ----------------
__global__ __launch_bounds__(TPB) void mul_sa(
    float* __restrict__ cbuf, const float* __restrict__ sa) {
  int i = blockIdx.x * TPB + threadIdx.x;
  int b = i >> 16;
  float4 g = ((const float4*)(sa + (size_t)b * 1024))[i & 255];
  float4 v = ((float4*)cbuf)[i];
  v.x *= g.x; v.y *= g.y; v.z *= g.z; v.w *= g.w;
  ((float4*)cbuf)[i] = v;
}

// ---------------- bf16 MFMA GEMM (3-pass): Y[b][o][n] = bias[o] + W[o,:]·X[b,:,n] ----------------
// W hi/lo [O][K]; X hi/lo [b][1024][256] transposed layout (k<256 -> Xa, else Xb).
// grid (16 n-tiles, O/64, 16 b), block 256 = 4 waves; wave w -> o-sub w*16, 64 n.
__global__ __launch_bounds__(TPB) void gemm_mfma(
    const unsigned short* __restrict__ Wh, const unsigned short* __restrict__ Wl,
    const float* __restrict__ bias,
    const unsigned short* __restrict__ Xah, const unsigned short* __restrict__ Xal,
    const unsigned short* __restrict__ Xbh, const unsigned short* __restrict__ Xbl,
    float* __restrict__ Y, int O, int K) {
  const int tid = threadIdx.x;
  const int n0 = blockIdx.x * 64, o0 = blockIdx.y * 64, b = blockIdx.z;
  const int w = tid >> 6, lane = tid & 63;
  const int l15 = lane & 15, cg = lane >> 4;
  const int orow = o0 + w * 16 + l15;

  f32x4 acc[4];
#pragma unroll
  for (int nf = 0; nf < 4; ++nf)
#pragma unroll
    for (int r = 0; r < 4; ++r) acc[nf][r] = 0.f;

  for (int k0 = 0; k0 < K; k0 += 32) {
    const unsigned short* Xh = Xah;
    const unsigned short* Xl = Xal;
    int kof = k0;
    if (k0 >= 256) { Xh = Xbh; Xl = Xbl; kof = k0 - 256; }
    bf16x8 wa_h = *(const bf16x8*)(Wh + (size_t)orow * K + k0 + cg * 8);
    bf16x8 wa_l = *(const bf16x8*)(Wl + (size_t)orow * K + k0 + cg * 8);
#pragma unroll
    for (int nf = 0; nf < 4; ++nf) {
      size_t g = ((size_t)(b * 1024 + n0 + nf * 16 + l15)) * 256 + kof + cg * 8;
      bf16x8 xh8 = *(const bf16x8*)(Xh + g);
      bf16x8 xl8 = *(const bf16x8*)(Xl + g);
      acc[nf] = __builtin_amdgcn_mfma_f32_16x16x32_bf16(wa_h, xh8, acc[nf], 0, 0, 0);
      acc[nf] = __builtin_amdgcn_mfma_f32_16x16x32_bf16(wa_h, xl8, acc[nf], 0, 0, 0);
      acc[nf] = __builtin_amdgcn_mfma_f32_16x16x32_bf16(wa_l, xh8, acc[nf], 0, 0, 0);
    }
  }
  // D: col(n)=l15, row(o)=cg*4+r
#pragma unroll
  for (int r = 0; r < 4; ++r) {
    int o = o0 + w * 16 + cg * 4 + r;
    float bv = bias[o];
    size_t base = ((size_t)b * O + o) * 1024 + n0 + l15;
#pragma unroll
    for (int nf = 0; nf < 4; ++nf) Y[base + nf * 16] = acc[nf][r] + bv;
  }
}

// ---------------- squared norms over channels ----------------
__global__ __launch_bounds__(TPB) void sqnorm(
    const float* __restrict__ src, float* __restrict__ dst, int CC) {
  int i = blockIdx.x * TPB + threadIdx.x;
  int b = i >> 10, n = i & 1023;
  const float* p = src + ((size_t)b * CC) * 1024 + n;
  float s = 0.f;
  for (int c = 0; c < CC; ++c) {
    float v = p[(size_t)c * 1024];
    s = fmaf(v, v, s);
  }
  dst[i] = s;
}

// ---------------- transpose+split: fp32 [b][128][1024] -> bf16 hi/lo [b][1024][128], rows XOR-swizzled ----------------
__global__ __launch_bounds__(TPB) void xpose_qk(
    const float* __restrict__ X, unsigned short* __restrict__ H,
    unsigned short* __restrict__ L) {
  __shared__ float xs[64 * 132];
  const int tid = threadIdx.x;
  const int n0 = blockIdx.x * 64, b = blockIdx.y;
#pragma unroll
  for (int i = 0; i < 8; ++i) {
    int idx = tid + i * TPB;
    int c = idx >> 4, nq = idx & 15;
    float4 f = *(const float4*)&X[((size_t)(b * 128 + c)) * 1024 + n0 + nq * 4];
    xs[(nq * 4 + 0) * 132 + c] = f.x;
    xs[(nq * 4 + 1) * 132 + c] = f.y;
    xs[(nq * 4 + 2) * 132 + c] = f.z;
    xs[(nq * 4 + 3) * 132 + c] = f.w;
  }
  __syncthreads();
#pragma unroll
  for (int i = 0; i < 4; ++i) {
    int idx = tid + i * TPB;
    int n = idx >> 4, oct = idx & 15;
    u16x8 h8, l8;
#pragma unroll
    for (int j = 0; j < 8; ++j) {
      float v = xs[n * 132 + oct * 8 + j];
      unsigned short h = f2bf(v);
      h8[j] = h;
      l8[j] = f2bf(v - bf2f(h));
    }
    int byteoff = (oct * 16) ^ ((n & 7) << 4);
    size_t rowbase = ((size_t)(b * 1024 + n0 + n)) * 256;  // bytes
    *(u16x8*)((char*)H + rowbase + byteoff) = h8;
    *(u16x8*)((char*)L + rowbase + byteoff) = l8;
  }
}

// ---------------- V convert: fp32 [b][256][1024] -> bf16 same layout, 128B-chunk swizzled by row ----------------
__global__ __launch_bounds__(TPB) void conv_v(
    const float* __restrict__ V, unsigned short* __restrict__ O) {
  int id = blockIdx.x * TPB + threadIdx.x;
  int j = id & 127, c = (id >> 7) & 255, b = id >> 15;
  const float* p = V + ((size_t)(b * 256 + c)) * 1024 + j * 8;
  float4 f0 = *(const float4*)p;
  float4 f1 = *(const float4*)(p + 4);
  u16x8 h8;
  h8[0] = f2bf(f0.x); h8[1] = f2bf(f0.y); h8[2] = f2bf(f0.z); h8[3] = f2bf(f0.w);
  h8[4] = f2bf(f1.x); h8[5] = f2bf(f1.y); h8[6] = f2bf(f1.z); h8[7] = f2bf(f1.w);
  size_t rowbase = ((size_t)(b * 256 + c)) * 2048;  // bytes
  int byteoff = (j * 16) ^ ((c & 7) << 4);
  *(u16x8*)((char*)O + rowbase + byteoff) = h8;
}

// ---------------- fused non-local attention via bf16 MFMA, adds into out in-place ----------------
__global__ __launch_bounds__(TPB, 2) void attn_mfma(
    const unsigned short* __restrict__ qth, const unsigned short* __restrict__ qtl,
    const unsigned short* __restrict__ kth, const unsigned short* __restrict__ ktl,
    const unsigned short* __restrict__ vt,
    const float* __restrict__ q2g, const float* __restrict__ k2g,
    const float* __restrict__ sigp, float* __restrict__ out) {
  __shared__ unsigned short ksh[64 * 128], ksl[64 * 128];
  __shared__ unsigned short vsm[256 * 64];
  __shared__ unsigned short pls[4][16 * 64];
  const int tid = threadIdx.x;
  const int b = blockIdx.y;
  const int n0 = blockIdx.x * 64;
  const int w = tid >> 6, lane = tid & 63;
  const int l15 = lane & 15, cg = lane >> 4;
  const float sg = *sigp;
  const float inv2s = 0.5f / (sg * sg);

  const int nq = n0 + w * 16 + l15;
  bf16x8 qh[4], ql[4];
  {
    const char* qrh = (const char*)qth + ((size_t)(b * 1024 + nq)) * 256;
    const char* qrl = (const char*)qtl + ((size_t)(b * 1024 + nq)) * 256;
    int sw = (nq & 7) << 4;
#pragma unroll
    for (int kc = 0; kc < 4; ++kc) {
      int o = (kc * 64 + cg * 16) ^ sw;
      qh[kc] = *(const bf16x8*)(qrh + o);
      ql[kc] = *(const bf16x8*)(qrl + o);
    }
  }
  float q2r[4];
#pragma unroll
  for (int r = 0; r < 4; ++r) q2r[r] = q2g[b * 1024 + n0 + w * 16 + cg * 4 + r];
  float dsum[4] = {0.f, 0.f, 0.f, 0.f};
  f32x4 acc[16];
#pragma unroll
  for (int cf = 0; cf < 16; ++cf)
#pragma unroll
    for (int r = 0; r < 4; ++r) acc[cf][r] = 0.f;

  const unsigned short* kh_g = kth + ((size_t)b * 1024) * 128;
  const unsigned short* kl_g = ktl + ((size_t)b * 1024) * 128;
  const unsigned short* v_g = vt + ((size_t)b * 256) * 1024;

  uint4 stg[16];
  auto load_tile = [&](int m0) {
#pragma unroll
    for (int i = 0; i < 4; ++i) {
      int off = (w + 4 * i) * 512 + lane * 8;
      stg[i] = *(const uint4*)(kh_g + (size_t)m0 * 128 + off);
      stg[4 + i] = *(const uint4*)(kl_g + (size_t)m0 * 128 + off);
    }
#pragma unroll
    for (int i = 0; i < 8; ++i) {
      int ch = w + 4 * i;
      int cp = ch * 8 + (lane >> 3);
      stg[8 + i] = *(const uint4*)(v_g + (size_t)cp * 1024 + m0 + (lane & 7) * 8);
    }
  };
  auto write_tile = [&]() {
#pragma unroll
    for (int i = 0; i < 4; ++i) {
      int off = (w + 4 * i) * 512 + lane * 8;
      *(uint4*)(ksh + off) = stg[i];
      *(uint4*)(ksl + off) = stg[4 + i];
    }
#pragma unroll
    for (int i = 0; i < 8; ++i) {
      int off = (w + 4 * i) * 512 + lane * 8;
      *(uint4*)(vsm + off) = stg[8 + i];
    }
  };

  load_tile(0);
  write_tile();
  __syncthreads();

  char* pmy = (char*)pls[w];
  const int psw = (l15 & 7) << 4;

  for (int t = 0; t < 16; ++t) {
    const int m0 = t * 64;
    float k2r[4];
#pragma unroll
    for (int mf = 0; mf < 4; ++mf) k2r[mf] = k2g[b * 1024 + m0 + mf * 16 + l15];
    if (t < 15) load_tile(m0 + 64);

    f32x4 s[4];
#pragma unroll
    for (int mf = 0; mf < 4; ++mf)
#pragma unroll
      for (int r = 0; r < 4; ++r) s[mf][r] = 0.f;
#pragma unroll
    for (int mf = 0; mf < 4; ++mf) {
      const char* krh = (const char*)ksh + (mf * 16 + l15) * 256;
      const char* krl = (const char*)ksl + (mf * 16 + l15) * 256;
      int sw = ((mf * 16 + l15) & 7) << 4;
#pragma unroll
      for (int kc = 0; kc < 4; ++kc) {
        int o = (kc * 64 + cg * 16) ^ sw;
        bf16x8 kh8 = *(const bf16x8*)(krh + o);
        bf16x8 kl8 = *(const bf16x8*)(krl + o);
        s[mf] = __builtin_amdgcn_mfma_f32_16x16x32_bf16(qh[kc], kh8, s[mf], 0, 0, 0);
        s[mf] = __builtin_amdgcn_mfma_f32_16x16x32_bf16(qh[kc], kl8, s[mf], 0, 0, 0);
        s[mf] = __builtin_amdgcn_mfma_f32_16x16x32_bf16(ql[kc], kh8, s[mf], 0, 0, 0);
      }
    }
#pragma unroll
    for (int mf = 0; mf < 4; ++mf) {
      int mloc = mf * 16 + l15;
#pragma unroll
      for (int r = 0; r < 4; ++r) {
        float d = q2r[r] + k2r[mf] - 2.f * s[mf][r];
        float sim = __expf(-d * inv2s);
        float p = __expf(sim);
        dsum[r] += p;
        int nl = cg * 4 + r;
        *(unsigned short*)(pmy + nl * 128 + ((mloc * 2) ^ ((nl & 7) << 4))) = f2bf(p);
      }
    }
    bf16x8 pa[2];
#pragma unroll
    for (int kc2 = 0; kc2 < 2; ++kc2)
      pa[kc2] = *(const bf16x8*)(pmy + l15 * 128 + ((kc2 * 64 + cg * 16) ^ psw));
#pragma unroll
    for (int cf = 0; cf < 16; ++cf) {
      int cp = cf * 16 + l15;
      const char* vrow = (const char*)vsm + cp * 128;
      int sw = (cp & 7) << 4;
#pragma unroll
      for (int kc2 = 0; kc2 < 2; ++kc2) {
        bf16x8 vb8 = *(const bf16x8*)(vrow + ((kc2 * 64 + cg * 16) ^ sw));
        acc[cf] = __builtin_amdgcn_mfma_f32_16x16x32_bf16(pa[kc2], vb8, acc[cf], 0, 0, 0);
      }
    }
    __syncthreads();
    if (t < 15) write_tile();
    __syncthreads();
  }

#pragma unroll
  for (int r = 0; r < 4; ++r) {
    dsum[r] += __shfl_xor(dsum[r], 1);
    dsum[r] += __shfl_xor(dsum[r], 2);
    dsum[r] += __shfl_xor(dsum[r], 4);
    dsum[r] += __shfl_xor(dsum[r], 8);
  }
#pragma unroll
  for (int r = 0; r < 4; ++r) {
    float rv = 1.f / dsum[r];
    size_t base = (size_t)b * 262144 + (size_t)(n0 + w * 16 + cg * 4 + r) * 256;
#pragma unroll
    for (int cf = 0; cf < 16; ++cf) {
      size_t idx = base + cf * 16 + l15;
      out[idx] += acc[cf][r] * rv;
    }
  }
}

// ---------------- launcher ----------------
extern "C" void kernel_launch(void* const* d_in, const int* in_sizes, int n_in,
                              void* d_out, int out_size, void* d_ws, size_t ws_size,
                              hipStream_t stream) {
  (void)in_sizes; (void)n_in; (void)out_size; (void)ws_size;
  const float* x      = (const float*)d_in[0];
  const float* w1     = (const float*)d_in[1];
  const float* b1     = (const float*)d_in[2];
  const float* w3     = (const float*)d_in[3];
  const float* b3     = (const float*)d_in[4];
  const float* w5     = (const float*)d_in[5];
  const float* b5     = (const float*)d_in[6];
  const float* wq     = (const float*)d_in[7];
  const float* bq     = (const float*)d_in[8];
  const float* wk     = (const float*)d_in[9];
  const float* bk     = (const float*)d_in[10];
  const float* wv     = (const float*)d_in[11];
  const float* bv     = (const float*)d_in[12];
  const float* sigma  = (const float*)d_in[13];
  const float* ca_w1  = (const float*)d_in[14];
  const float* ca_w2  = (const float*)d_in[15];
  const float* sa_w   = (const float*)d_in[16];
  const float* tail_w = (const float*)d_in[17];
  const float* tail_b = (const float*)d_in[18];
  float* out_f = (float*)d_out;

  float* ws = (float*)d_ws;
  float* outb  = ws;  ws += 4194304;
  float* cbuf  = ws;  ws += 4194304;
  float* qb    = ws;  ws += 2097152;   // fp32 q; later vtb (bf16 V, 8MB exact)
  float* kb    = ws;  ws += 2097152;
  float* vb    = ws;  ws += 4194304;   // fp32 v; later tail-part2 bf16 hi/lo (16MB exact)
  float* b_eff = ws;  ws += 256;
  float* avg   = ws;  ws += 4096;
  float* mxp   = ws;  ws += 4096;
  float* cab   = ws;  ws += 4096;
  float* sain  = ws;  ws += 32768;
  float* sab   = ws;  ws += 16384;
  float* q2b   = ws;  ws += 16384;
  float* k2b   = ws;  ws += 16384;
  unsigned short* us = (unsigned short*)ws;
  unsigned short* wfh = us;  us += 1638400;   // conv weights hi
  unsigned short* wfl = us;  us += 1638400;   // conv weights lo
  unsigned short* xhb = us;  us += 4194304;   // x-hi -> act-hi -> qth/qtl -> cbuf-hi
  unsigned short* xlb = us;  us += 4194304;   // x-lo -> act-lo -> kth/ktl -> cbuf-lo
  unsigned short* wqh = us;  us += 32768;
  unsigned short* wql = us;  us += 32768;
  unsigned short* wkh = us;  us += 32768;
  unsigned short* wkl = us;  us += 32768;
  unsigned short* wvh = us;  us += 65536;
  unsigned short* wvl = us;  us += 65536;
  unsigned short* twh = us;  us += 131072;
  unsigned short* twl = us;  us += 131072;
  unsigned short* qth = xhb;
  unsigned short* qtl = xhb + 2097152;
  unsigned short* kth = xlb;
  unsigned short* ktl = xlb + 2097152;
  unsigned short* vtb = (unsigned short*)qb;  // 8MB region
  unsigned short* ah  = xhb;                  // activations-hi [b][n][256]
  unsigned short* al  = xlb;
  unsigned short* bh  = (unsigned short*)vb;  // tail part2 hi
  unsigned short* bl  = bh + 4194304;

  // 0. weight preps
  hipLaunchKernelGGL(prep_w, dim3(6400), dim3(TPB), 0, stream,
                     w1, b1, w3, b3, w5, b5, wfh, wfl, b_eff);
  hipLaunchKernelGGL(prep_wgt, dim3(128), dim3(TPB), 0, stream, wq, wqh, wql, 32768);
  hipLaunchKernelGGL(prep_wgt, dim3(128), dim3(TPB), 0, stream, wk, wkh, wkl, 32768);
  hipLaunchKernelGGL(prep_wgt, dim3(256), dim3(TPB), 0, stream, wv, wvh, wvl, 65536);
  hipLaunchKernelGGL(prep_wgt, dim3(512), dim3(TPB), 0, stream, tail_w, twh, twl, 131072);
  // 1. x conv (bf16 MFMA, 3-pass)
  hipLaunchKernelGGL(prep_x, dim3(2048), dim3(TPB), 0, stream, x, xhb, xlb);
  hipLaunchKernelGGL(conv5_mfma, dim3(8, 4, 16), dim3(TPB), 0, stream,
                     xhb, xlb, wfh, wfl, b_eff, outb);
  // 2. CBAM
  hipLaunchKernelGGL(pool_avgmax, dim3(4096), dim3(TPB), 0, stream, outb, avg, mxp);
  hipLaunchKernelGGL(ca_mlp, dim3(16), dim3(TPB), 0, stream, avg, mxp, ca_w1, ca_w2, cab);
  hipLaunchKernelGGL(mul_ca, dim3(4096), dim3(TPB), 0, stream, outb, cab, cbuf);
  hipLaunchKernelGGL(spatial_pool, dim3(64), dim3(TPB), 0, stream, cbuf, sain);
  hipLaunchKernelGGL(sa_conv, dim3(64), dim3(TPB), 0, stream, sain, sa_w, sab);
  hipLaunchKernelGGL(mul_sa, dim3(4096), dim3(TPB), 0, stream, cbuf, sab);
  // 3. q/k/v GEMMs (bf16 MFMA) on transposed activations
  hipLaunchKernelGGL(prep_x, dim3(2048), dim3(TPB), 0, stream, outb, ah, al);
  hipLaunchKernelGGL(gemm_mfma, dim3(16, 2, 16), dim3(TPB), 0, stream,
                     wqh, wql, bq, ah, al, ah, al, qb, 128, 256);
  hipLaunchKernelGGL(gemm_mfma, dim3(16, 2, 16), dim3(TPB), 0, stream,
                     wkh, wkl, bk, ah, al, ah, al, kb, 128, 256);
  hipLaunchKernelGGL(gemm_mfma, dim3(16, 4, 16), dim3(TPB), 0, stream,
                     wvh, wvl, bv, ah, al, ah, al, vb, 256, 256);
  // 4. attention preps (qth/qtl overwrite ah region — ah dead after gemms)
  hipLaunchKernelGGL(sqnorm, dim3(64), dim3(TPB), 0, stream, qb, q2b, 128);
  hipLaunchKernelGGL(sqnorm, dim3(64), dim3(TPB), 0, stream, kb, k2b, 128);
  hipLaunchKernelGGL(xpose_qk, dim3(16, 16), dim3(TPB), 0, stream, qb, qth, qtl);
  hipLaunchKernelGGL(xpose_qk, dim3(16, 16), dim3(TPB), 0, stream, kb, kth, ktl);
  hipLaunchKernelGGL(conv_v, dim3(2048), dim3(TPB), 0, stream, vb, vtb);  // qb dead
  hipLaunchKernelGGL(attn_mfma, dim3(16, 16), dim3(TPB), 0, stream,
                     qth, qtl, kth, ktl, vtb, q2b, k2b, sigma, outb);
  // 5. tail GEMM over concat [cbam_out(cbuf), non_local(outb)]
  hipLaunchKernelGGL(prep_x, dim3(2048), dim3(TPB), 0, stream, cbuf, ah, al);  // qth dead
  hipLaunchKernelGGL(prep_x, dim3(2048), dim3(TPB), 0, stream, outb, bh, bl);  // vb dead
  hipLaunchKernelGGL(gemm_mfma, dim3(16, 4, 16), dim3(TPB), 0, stream,
                     twh, twl, tail_b, ah, al, bh, bl, out_f, 256, 512);
}

// Round 8
// 510.097 us; speedup vs baseline: 1.8322x; 1.8322x over previous
//
#include <hip/hip_runtime.h>
#include <cstddef>

#define TPB 256

typedef __bf16 bf16x8 __attribute__((ext_vector_type(8)));
typedef _Float16 f16x8 __attribute__((ext_vector_type(8)));
typedef float f32x4 __attribute__((ext_vector_type(4)));
typedef unsigned short u16x8 __attribute__((ext_vector_type(8)));

__device__ __forceinline__ unsigned short f2bf(float f) {
  unsigned u = __float_as_uint(f);
  unsigned r = (u + 0x7FFFu + ((u >> 16) & 1u)) >> 16;
  return (unsigned short)r;
}
__device__ __forceinline__ float bf2f(unsigned short h) {
  return __uint_as_float(((unsigned)h) << 16);
}
__device__ __forceinline__ unsigned short f2h(float v) {
  _Float16 h = (_Float16)v;
  unsigned short u;
  __builtin_memcpy(&u, &h, 2);
  return u;
}

// ---------------- P0: merged conv weights -> fp16 [tap][oc][c] ----------------
__global__ __launch_bounds__(TPB) void prep_w(
    const float* __restrict__ w1, const float* __restrict__ b1,
    const float* __restrict__ w3, const float* __restrict__ b3,
    const float* __restrict__ w5, const float* __restrict__ b5,
    unsigned short* __restrict__ wh, float* __restrict__ b_eff) {
  int i = blockIdx.x * TPB + threadIdx.x;  // < 25*65536
  int tap = i >> 16;
  int oc = (i >> 8) & 255;
  int c = i & 255;
  int kh = tap / 5, kw = tap - kh * 5;
  size_t occ = (size_t)((oc << 8) | c);
  float v = w5[occ * 25 + tap];
  if (kh >= 1 && kh <= 3 && kw >= 1 && kw <= 3)
    v += w3[occ * 9 + (kh - 1) * 3 + (kw - 1)];
  if (tap == 12) v += w1[occ];
  wh[i] = f2h(v);
  if (i < 256) b_eff[i] = b1[i] + b3[i] + b5[i];
}

// ---------------- P1: fp32 [b][256][1024] -> fp16 [b][1024][256] ----------------
__global__ __launch_bounds__(TPB) void prep_xh(
    const float* __restrict__ x, unsigned short* __restrict__ xh) {
  int i = blockIdx.x * TPB + threadIdx.x;  // < 16*32*1024
  int b = i >> 15, cg = (i >> 10) & 31, pix = i & 1023;
  u16x8 h8;
#pragma unroll
  for (int j = 0; j < 8; ++j)
    h8[j] = f2h(x[((size_t)(b * 256 + cg * 8 + j)) * 1024 + pix]);
  *(u16x8*)(xh + ((size_t)(b * 1024 + pix)) * 256 + cg * 8) = h8;
}

// ---------------- P2: generic weight fp32 -> fp16 ----------------
__global__ __launch_bounds__(TPB) void prep_wgt(
    const float* __restrict__ w, unsigned short* __restrict__ h, int n) {
  int i = blockIdx.x * TPB + threadIdx.x;
  if (i < n) h[i] = f2h(w[i]);
}

// ---------------- K1: fused 5x5 conv, fp16 MFMA single-pass ----------------
// grid (16 h-tiles of 2 rows, 4 oc-tiles, 16 b), block 256 = 4 waves.
// wave w: row h0+(w&1), oc half (w>>1)*32. LDS: x halo [6 rows][36 cols][32c],
// per-tap B [64oc][32c] double-buffered. Chunk-XOR ch^((row>>1)&3): reads
// conflict-free, writes <=2-way. 1 barrier/tap.
__global__ __launch_bounds__(TPB) void conv5_mfma(
    const unsigned short* __restrict__ xh, const unsigned short* __restrict__ wh,
    const float* __restrict__ b_eff, float* __restrict__ out) {
  __shared__ unsigned short xs[216 * 32];
  __shared__ unsigned short bs[2][64 * 32];
  const int tid = threadIdx.x;
  const int h0 = blockIdx.x * 2;
  const int oc0 = blockIdx.y * 64;
  const int b = blockIdx.z;
  const int lane = tid & 63;
  const int w = tid >> 6;
  const int wr = w & 1, wo = w >> 1;
  const int l15 = lane & 15, cg = lane >> 4;

  f32x4 acc[2][2];
#pragma unroll
  for (int mf = 0; mf < 2; ++mf)
#pragma unroll
    for (int nf = 0; nf < 2; ++nf)
#pragma unroll
      for (int r = 0; r < 4; ++r) acc[mf][nf][r] = 0.f;

  const int s_oc = tid >> 2, s_ch = tid & 3;
  const int bso = s_oc * 32 + ((s_ch ^ ((s_oc >> 1) & 3)) * 8);
  const size_t bgbase = (size_t)(oc0 + s_oc) * 256 + s_ch * 8;

  uint4 breg;
  for (int c0 = 0; c0 < 256; c0 += 32) {
    breg = *(const uint4*)(wh + bgbase + c0);  // tap 0, issued before barrier
    __syncthreads();  // prev c0 readers done
    // stage x halo: 216 sites x 4 chunks = 864 tasks
#pragma unroll
    for (int it = 0; it < 4; ++it) {
      int e = tid + it * TPB;
      if (e < 864) {
        int site = e >> 2, ch = e & 3;
        int row = site / 36, col = site - row * 36;
        int ih = h0 + row - 2, iw = col - 2;
        uint4 v = {0u, 0u, 0u, 0u};
        if ((unsigned)ih < 32u && (unsigned)iw < 32u)
          v = *(const uint4*)(xh + ((size_t)(b * 1024 + ih * 32 + iw)) * 256 + c0 + ch * 8);
        *(uint4*)(xs + site * 32 + ((ch ^ ((site >> 1) & 3)) * 8)) = v;
      }
    }
    *(uint4*)(bs[0] + bso) = breg;
    __syncthreads();
    int cur = 0;
#pragma unroll
    for (int kh = 0; kh < 5; ++kh) {
#pragma unroll
      for (int kw = 0; kw < 5; ++kw) {
        const int tap = kh * 5 + kw;
        if (tap < 24)
          breg = *(const uint4*)(wh + (size_t)(tap + 1) * 65536 + bgbase + c0);
        f16x8 A[2], B[2];
#pragma unroll
        for (int mf = 0; mf < 2; ++mf) {
          int as = (wr + kh) * 36 + mf * 16 + l15 + kw;
          A[mf] = *(const f16x8*)(xs + as * 32 + ((cg ^ ((as >> 1) & 3)) * 8));
        }
#pragma unroll
        for (int nf = 0; nf < 2; ++nf) {
          int oc = wo * 32 + nf * 16 + l15;
          B[nf] = *(const f16x8*)(bs[cur] + oc * 32 + ((cg ^ ((oc >> 1) & 3)) * 8));
        }
#pragma unroll
        for (int mf = 0; mf < 2; ++mf)
#pragma unroll
          for (int nf = 0; nf < 2; ++nf)
            acc[mf][nf] = __builtin_amdgcn_mfma_f32_16x16x32_f16(A[mf], B[nf], acc[mf][nf], 0, 0, 0);
        if (tap < 24) {
          *(uint4*)(bs[cur ^ 1] + bso) = breg;
          cur ^= 1;
          __syncthreads();
        }
      }
    }
  }

  // D: row(pixel col)=cg*4+r, col(oc)=l15
#pragma unroll
  for (int mf = 0; mf < 2; ++mf)
#pragma unroll
    for (int nf = 0; nf < 2; ++nf) {
      int oc = oc0 + wo * 32 + nf * 16 + l15;
      float bv = b_eff[oc];
      size_t base = ((size_t)(b * 256 + oc)) * 1024 + (h0 + wr) * 32 + mf * 16 + cg * 4;
      float4 r;
      r.x = acc[mf][nf][0] + bv;
      r.y = acc[mf][nf][1] + bv;
      r.z = acc[mf][nf][2] + bv;
      r.w = acc[mf][nf][3] + bv;
      *(float4*)(out + base) = r;
    }
}

// ---------------- K2: per-(b,c) avg+max pool ----------------
__global__ __launch_bounds__(TPB) void pool_avgmax(
    const float* __restrict__ out, float* __restrict__ avg, float* __restrict__ mx) {
  int bc = blockIdx.x;
  int tid = threadIdx.x;
  const float4 v = ((const float4*)(out + (size_t)bc * 1024))[tid];
  float s = v.x + v.y + v.z + v.w;
  float m = fmaxf(fmaxf(v.x, v.y), fmaxf(v.z, v.w));
#pragma unroll
  for (int off = 1; off < 64; off <<= 1) {
    s += __shfl_xor(s, off);
    m = fmaxf(m, __shfl_xor(m, off));
  }
  __shared__ float ss[4], ms[4];
  if ((tid & 63) == 0) { ss[tid >> 6] = s; ms[tid >> 6] = m; }
  __syncthreads();
  if (tid == 0) {
    s = ss[0] + ss[1] + ss[2] + ss[3];
    m = fmaxf(fmaxf(ms[0], ms[1]), fmaxf(ms[2], ms[3]));
    avg[bc] = s * (1.f / 1024.f);
    mx[bc] = m;
  }
}

// ---------------- K3: channel-attention MLP ----------------
__global__ __launch_bounds__(TPB) void ca_mlp(
    const float* __restrict__ avg, const float* __restrict__ mx,
    const float* __restrict__ w1, const float* __restrict__ w2,
    float* __restrict__ ca) {
  int b = blockIdx.x;
  int t = threadIdx.x;
  __shared__ float av[256], mv[256], h[16];
  av[t] = avg[b * 256 + t];
  mv[t] = mx[b * 256 + t];
  __syncthreads();
  if (t < 16) {
    float ha = 0.f, hm = 0.f;
    for (int c = 0; c < 256; ++c) {
      float wv = w1[t * 256 + c];
      ha += wv * av[c];
      hm += wv * mv[c];
    }
    h[t] = fmaxf(ha, 0.f) + fmaxf(hm, 0.f);
  }
  __syncthreads();
  float s = 0.f;
#pragma unroll
  for (int j = 0; j < 16; ++j) s += w2[t * 16 + j] * h[j];
  ca[b * 256 + t] = 1.f / (1.f + __expf(-s));
}

// ---------------- K4: c = out * ca ----------------
__global__ __launch_bounds__(TPB) void mul_ca(
    const float* __restrict__ out, const float* __restrict__ ca,
    float* __restrict__ cbuf) {
  int i = blockIdx.x * TPB + threadIdx.x;
  float4 v = ((const float4*)out)[i];
  float g = ca[i >> 8];
  v.x *= g; v.y *= g; v.z *= g; v.w *= g;
  ((float4*)cbuf)[i] = v;
}

// ---------------- K5: spatial mean/max over channels ----------------
__global__ __launch_bounds__(TPB) void spatial_pool(
    const float* __restrict__ cbuf, float* __restrict__ sa_in) {
  int i = blockIdx.x * TPB + threadIdx.x;
  int b = i >> 10, pix = i & 1023;
  const float* p = cbuf + (size_t)b * 262144 + pix;
  float s = 0.f, m = -3.4e38f;
  for (int ch = 0; ch < 256; ++ch) {
    float v = p[(size_t)ch * 1024];
    s += v;
    m = fmaxf(m, v);
  }
  sa_in[b * 2048 + pix] = s * (1.f / 256.f);
  sa_in[b * 2048 + 1024 + pix] = m;
}

// ---------------- K6: 7x7 spatial-attn conv + sigmoid ----------------
__global__ __launch_bounds__(TPB) void sa_conv(
    const float* __restrict__ sa_in, const float* __restrict__ sw,
    float* __restrict__ sa) {
  int i = blockIdx.x * TPB + threadIdx.x;
  int b = i >> 10, pix = i & 1023;
  int h = pix >> 5, w = pix & 31;
  float s = 0.f;
#pragma unroll
  for (int ci = 0; ci < 2; ++ci)
    for (int kh = 0; kh < 7; ++kh) {
      int ih = h + kh - 3;
      if ((unsigned)ih >= 32u) continue;
#pragma unroll
      for (int kw = 0; kw < 7; ++kw) {
        int iw = w + kw - 3;
        if ((unsigned)iw >= 32u) continue;
        s += sa_in[b * 2048 + ci * 1024 + ih * 32 + iw] * sw[ci * 49 + kh * 7 + kw];
      }
    }
  sa[i] = 1.f / (1.f + __expf(-s));
}

// ---------------- K7: cbam = c * sa ----------------
__global__ __launch_bounds__(TPB) void mul_sa(
    float* __restrict__ cbuf, const float* __restrict__ sa) {
  int i = blockIdx.x * TPB + threadIdx.x;
  int b = i >> 16;
  float4 g = ((const float4*)(sa + (size_t)b * 1024))[i & 255];
  float4 v = ((float4*)cbuf)[i];
  v.x *= g.x; v.y *= g.y; v.z *= g.z; v.w *= g.w;
  ((float4*)cbuf)[i] = v;
}

// ---------------- fp16 MFMA GEMM 1-pass: Y[b][o][n] = bias[o] + W[o,:]·X[b,n,:] ----------------
// X fp16 [b][1024][256] (k<256 -> Xa, else Xb). LDS dbuf W/X tiles, 1 barrier/chunk.
__global__ __launch_bounds__(TPB) void gemm_mfma(
    const unsigned short* __restrict__ Wh, const float* __restrict__ bias,
    const unsigned short* __restrict__ Xah, const unsigned short* __restrict__ Xbh,
    float* __restrict__ Y, int O, int K) {
  __shared__ unsigned short Wsm[2][64 * 32], Xsm[2][64 * 32];
  const int tid = threadIdx.x;
  const int n0 = blockIdx.x * 64, o0 = blockIdx.y * 64, b = blockIdx.z;
  const int w = tid >> 6, lane = tid & 63;
  const int l15 = lane & 15, cg = lane >> 4;
  const int s_r = tid >> 2, s_ch = tid & 3;
  const int so = s_r * 32 + ((s_ch ^ ((s_r >> 1) & 3)) * 8);

  f32x4 acc[4];
#pragma unroll
  for (int nf = 0; nf < 4; ++nf)
#pragma unroll
    for (int r = 0; r < 4; ++r) acc[nf][r] = 0.f;

  const int nch = K >> 5;
  uint4 wreg, xreg;
  auto loadc = [&](int kc) {
    int k0 = kc << 5;
    const unsigned short* Xp = Xah;
    int kof = k0;
    if (k0 >= 256) { Xp = Xbh; kof = k0 - 256; }
    wreg = *(const uint4*)(Wh + (size_t)(o0 + s_r) * K + k0 + s_ch * 8);
    xreg = *(const uint4*)(Xp + ((size_t)(b * 1024 + n0 + s_r)) * 256 + kof + s_ch * 8);
  };
  loadc(0);
  *(uint4*)(Wsm[0] + so) = wreg;
  *(uint4*)(Xsm[0] + so) = xreg;
  __syncthreads();
  int cur = 0;
  for (int kc = 0; kc < nch; ++kc) {
    if (kc + 1 < nch) loadc(kc + 1);
    const int orow = w * 16 + l15;
    f16x8 a = *(const f16x8*)(Wsm[cur] + orow * 32 + ((cg ^ ((orow >> 1) & 3)) * 8));
#pragma unroll
    for (int nf = 0; nf < 4; ++nf) {
      int nr = nf * 16 + l15;
      f16x8 xb = *(const f16x8*)(Xsm[cur] + nr * 32 + ((cg ^ ((nr >> 1) & 3)) * 8));
      acc[nf] = __builtin_amdgcn_mfma_f32_16x16x32_f16(a, xb, acc[nf], 0, 0, 0);
    }
    if (kc + 1 < nch) {
      *(uint4*)(Wsm[cur ^ 1] + so) = wreg;
      *(uint4*)(Xsm[cur ^ 1] + so) = xreg;
      cur ^= 1;
      __syncthreads();
    }
  }
  // D: col(n)=l15, row(o)=cg*4+r
#pragma unroll
  for (int r = 0; r < 4; ++r) {
    int o = o0 + w * 16 + cg * 4 + r;
    float bv = bias[o];
    size_t base = ((size_t)b * O + o) * 1024 + n0 + l15;
#pragma unroll
    for (int nf = 0; nf < 4; ++nf) Y[base + nf * 16] = acc[nf][r] + bv;
  }
}

// ---------------- squared norms over channels ----------------
__global__ __launch_bounds__(TPB) void sqnorm(
    const float* __restrict__ src, float* __restrict__ dst, int CC) {
  int i = blockIdx.x * TPB + threadIdx.x;
  int b = i >> 10, n = i & 1023;
  const float* p = src + ((size_t)b * CC) * 1024 + n;
  float s = 0.f;
  for (int c = 0; c < CC; ++c) {
    float v = p[(size_t)c * 1024];
    s = fmaf(v, v, s);
  }
  dst[i] = s;
}

// ---------------- transpose+split: fp32 [b][128][1024] -> bf16 hi/lo [b][1024][128], swizzled ----------------
__global__ __launch_bounds__(TPB) void xpose_qk(
    const float* __restrict__ X, unsigned short* __restrict__ H,
    unsigned short* __restrict__ L) {
  __shared__ float xs[64 * 132];
  const int tid = threadIdx.x;
  const int n0 = blockIdx.x * 64, b = blockIdx.y;
#pragma unroll
  for (int i = 0; i < 8; ++i) {
    int idx = tid + i * TPB;
    int c = idx >> 4, nq = idx & 15;
    float4 f = *(const float4*)&X[((size_t)(b * 128 + c)) * 1024 + n0 + nq * 4];
    xs[(nq * 4 + 0) * 132 + c] = f.x;
    xs[(nq * 4 + 1) * 132 + c] = f.y;
    xs[(nq * 4 + 2) * 132 + c] = f.z;
    xs[(nq * 4 + 3) * 132 + c] = f.w;
  }
  __syncthreads();
#pragma unroll
  for (int i = 0; i < 4; ++i) {
    int idx = tid + i * TPB;
    int n = idx >> 4, oct = idx & 15;
    u16x8 h8, l8;
#pragma unroll
    for (int j = 0; j < 8; ++j) {
      float v = xs[n * 132 + oct * 8 + j];
      unsigned short h = f2bf(v);
      h8[j] = h;
      l8[j] = f2bf(v - bf2f(h));
    }
    int byteoff = (oct * 16) ^ ((n & 7) << 4);
    size_t rowbase = ((size_t)(b * 1024 + n0 + n)) * 256;  // bytes
    *(u16x8*)((char*)H + rowbase + byteoff) = h8;
    *(u16x8*)((char*)L + rowbase + byteoff) = l8;
  }
}

// ---------------- V convert: fp32 [b][256][1024] -> bf16 same layout, swizzled ----------------
__global__ __launch_bounds__(TPB) void conv_v(
    const float* __restrict__ V, unsigned short* __restrict__ O) {
  int id = blockIdx.x * TPB + threadIdx.x;
  int j = id & 127, c = (id >> 7) & 255, b = id >> 15;
  const float* p = V + ((size_t)(b * 256 + c)) * 1024 + j * 8;
  float4 f0 = *(const float4*)p;
  float4 f1 = *(const float4*)(p + 4);
  u16x8 h8;
  h8[0] = f2bf(f0.x); h8[1] = f2bf(f0.y); h8[2] = f2bf(f0.z); h8[3] = f2bf(f0.w);
  h8[4] = f2bf(f1.x); h8[5] = f2bf(f1.y); h8[6] = f2bf(f1.z); h8[7] = f2bf(f1.w);
  size_t rowbase = ((size_t)(b * 256 + c)) * 2048;  // bytes
  int byteoff = (j * 16) ^ ((c & 7) << 4);
  *(u16x8*)((char*)O + rowbase + byteoff) = h8;
}

// ---------------- fused non-local attention via bf16 MFMA (3-pass QK^T) ----------------
__global__ __launch_bounds__(TPB, 2) void attn_mfma(
    const unsigned short* __restrict__ qth, const unsigned short* __restrict__ qtl,
    const unsigned short* __restrict__ kth, const unsigned short* __restrict__ ktl,
    const unsigned short* __restrict__ vt,
    const float* __restrict__ q2g, const float* __restrict__ k2g,
    const float* __restrict__ sigp, float* __restrict__ out) {
  __shared__ unsigned short ksh[64 * 128], ksl[64 * 128];
  __shared__ unsigned short vsm[256 * 64];
  __shared__ unsigned short pls[4][16 * 64];
  const int tid = threadIdx.x;
  const int b = blockIdx.y;
  const int n0 = blockIdx.x * 64;
  const int w = tid >> 6, lane = tid & 63;
  const int l15 = lane & 15, cg = lane >> 4;
  const float sg = *sigp;
  const float inv2s = 0.5f / (sg * sg);

  const int nq = n0 + w * 16 + l15;
  bf16x8 qh[4], ql[4];
  {
    const char* qrh = (const char*)qth + ((size_t)(b * 1024 + nq)) * 256;
    const char* qrl = (const char*)qtl + ((size_t)(b * 1024 + nq)) * 256;
    int sw = (nq & 7) << 4;
#pragma unroll
    for (int kc = 0; kc < 4; ++kc) {
      int o = (kc * 64 + cg * 16) ^ sw;
      qh[kc] = *(const bf16x8*)(qrh + o);
      ql[kc] = *(const bf16x8*)(qrl + o);
    }
  }
  float q2r[4];
#pragma unroll
  for (int r = 0; r < 4; ++r) q2r[r] = q2g[b * 1024 + n0 + w * 16 + cg * 4 + r];
  float dsum[4] = {0.f, 0.f, 0.f, 0.f};
  f32x4 acc[16];
#pragma unroll
  for (int cf = 0; cf < 16; ++cf)
#pragma unroll
    for (int r = 0; r < 4; ++r) acc[cf][r] = 0.f;

  const unsigned short* kh_g = kth + ((size_t)b * 1024) * 128;
  const unsigned short* kl_g = ktl + ((size_t)b * 1024) * 128;
  const unsigned short* v_g = vt + ((size_t)b * 256) * 1024;

  uint4 stg[16];
  auto load_tile = [&](int m0) {
#pragma unroll
    for (int i = 0; i < 4; ++i) {
      int off = (w + 4 * i) * 512 + lane * 8;
      stg[i] = *(const uint4*)(kh_g + (size_t)m0 * 128 + off);
      stg[4 + i] = *(const uint4*)(kl_g + (size_t)m0 * 128 + off);
    }
#pragma unroll
    for (int i = 0; i < 8; ++i) {
      int ch = w + 4 * i;
      int cp = ch * 8 + (lane >> 3);
      stg[8 + i] = *(const uint4*)(v_g + (size_t)cp * 1024 + m0 + (lane & 7) * 8);
    }
  };
  auto write_tile = [&]() {
#pragma unroll
    for (int i = 0; i < 4; ++i) {
      int off = (w + 4 * i) * 512 + lane * 8;
      *(uint4*)(ksh + off) = stg[i];
      *(uint4*)(ksl + off) = stg[4 + i];
    }
#pragma unroll
    for (int i = 0; i < 8; ++i) {
      int off = (w + 4 * i) * 512 + lane * 8;
      *(uint4*)(vsm + off) = stg[8 + i];
    }
  };

  load_tile(0);
  write_tile();
  __syncthreads();

  char* pmy = (char*)pls[w];
  const int psw = (l15 & 7) << 4;

  for (int t = 0; t < 16; ++t) {
    const int m0 = t * 64;
    float k2r[4];
#pragma unroll
    for (int mf = 0; mf < 4; ++mf) k2r[mf] = k2g[b * 1024 + m0 + mf * 16 + l15];
    if (t < 15) load_tile(m0 + 64);

    f32x4 s[4];
#pragma unroll
    for (int mf = 0; mf < 4; ++mf)
#pragma unroll
      for (int r = 0; r < 4; ++r) s[mf][r] = 0.f;
#pragma unroll
    for (int mf = 0; mf < 4; ++mf) {
      const char* krh = (const char*)ksh + (mf * 16 + l15) * 256;
      const char* krl = (const char*)ksl + (mf * 16 + l15) * 256;
      int sw = ((mf * 16 + l15) & 7) << 4;
#pragma unroll
      for (int kc = 0; kc < 4; ++kc) {
        int o = (kc * 64 + cg * 16) ^ sw;
        bf16x8 kh8 = *(const bf16x8*)(krh + o);
        bf16x8 kl8 = *(const bf16x8*)(krl + o);
        s[mf] = __builtin_amdgcn_mfma_f32_16x16x32_bf16(qh[kc], kh8, s[mf], 0, 0, 0);
        s[mf] = __builtin_amdgcn_mfma_f32_16x16x32_bf16(qh[kc], kl8, s[mf], 0, 0, 0);
        s[mf] = __builtin_amdgcn_mfma_f32_16x16x32_bf16(ql[kc], kh8, s[mf], 0, 0, 0);
      }
    }
#pragma unroll
    for (int mf = 0; mf < 4; ++mf) {
      int mloc = mf * 16 + l15;
#pragma unroll
      for (int r = 0; r < 4; ++r) {
        float d = q2r[r] + k2r[mf] - 2.f * s[mf][r];
        float sim = __expf(-d * inv2s);
        float p = __expf(sim);
        dsum[r] += p;
        int nl = cg * 4 + r;
        *(unsigned short*)(pmy + nl * 128 + ((mloc * 2) ^ ((nl & 7) << 4))) = f2bf(p);
      }
    }
    bf16x8 pa[2];
#pragma unroll
    for (int kc2 = 0; kc2 < 2; ++kc2)
      pa[kc2] = *(const bf16x8*)(pmy + l15 * 128 + ((kc2 * 64 + cg * 16) ^ psw));
#pragma unroll
    for (int cf = 0; cf < 16; ++cf) {
      int cp = cf * 16 + l15;
      const char* vrow = (const char*)vsm + cp * 128;
      int sw = (cp & 7) << 4;
#pragma unroll
      for (int kc2 = 0; kc2 < 2; ++kc2) {
        bf16x8 vb8 = *(const bf16x8*)(vrow + ((kc2 * 64 + cg * 16) ^ sw));
        acc[cf] = __builtin_amdgcn_mfma_f32_16x16x32_bf16(pa[kc2], vb8, acc[cf], 0, 0, 0);
      }
    }
    __syncthreads();
    if (t < 15) write_tile();
    __syncthreads();
  }

#pragma unroll
  for (int r = 0; r < 4; ++r) {
    dsum[r] += __shfl_xor(dsum[r], 1);
    dsum[r] += __shfl_xor(dsum[r], 2);
    dsum[r] += __shfl_xor(dsum[r], 4);
    dsum[r] += __shfl_xor(dsum[r], 8);
  }
#pragma unroll
  for (int r = 0; r < 4; ++r) {
    float rv = 1.f / dsum[r];
    size_t base = (size_t)b * 262144 + (size_t)(n0 + w * 16 + cg * 4 + r) * 256;
#pragma unroll
    for (int cf = 0; cf < 16; ++cf) {
      size_t idx = base + cf * 16 + l15;
      out[idx] += acc[cf][r] * rv;
    }
  }
}

// ---------------- launcher ----------------
extern "C" void kernel_launch(void* const* d_in, const int* in_sizes, int n_in,
                              void* d_out, int out_size, void* d_ws, size_t ws_size,
                              hipStream_t stream) {
  (void)in_sizes; (void)n_in; (void)out_size; (void)ws_size;
  const float* x      = (const float*)d_in[0];
  const float* w1     = (const float*)d_in[1];
  const float* b1     = (const float*)d_in[2];
  const float* w3     = (const float*)d_in[3];
  const float* b3     = (const float*)d_in[4];
  const float* w5     = (const float*)d_in[5];
  const float* b5     = (const float*)d_in[6];
  const float* wq     = (const float*)d_in[7];
  const float* bq     = (const float*)d_in[8];
  const float* wk     = (const float*)d_in[9];
  const float* bk     = (const float*)d_in[10];
  const float* wv     = (const float*)d_in[11];
  const float* bv     = (const float*)d_in[12];
  const float* sigma  = (const float*)d_in[13];
  const float* ca_w1  = (const float*)d_in[14];
  const float* ca_w2  = (const float*)d_in[15];
  const float* sa_w   = (const float*)d_in[16];
  const float* tail_w = (const float*)d_in[17];
  const float* tail_b = (const float*)d_in[18];
  float* out_f = (float*)d_out;

  float* ws = (float*)d_ws;
  float* outb  = ws;  ws += 4194304;
  float* cbuf  = ws;  ws += 4194304;
  float* qb    = ws;  ws += 2097152;   // fp32 q; later vtb (bf16 V)
  float* kb    = ws;  ws += 2097152;
  float* vb    = ws;  ws += 4194304;   // fp32 v; later tail-part2 fp16
  float* b_eff = ws;  ws += 256;
  float* avg   = ws;  ws += 4096;
  float* mxp   = ws;  ws += 4096;
  float* cab   = ws;  ws += 4096;
  float* sain  = ws;  ws += 32768;
  float* sab   = ws;  ws += 16384;
  float* q2b   = ws;  ws += 16384;
  float* k2b   = ws;  ws += 16384;
  unsigned short* us = (unsigned short*)ws;
  unsigned short* wfh  = us;  us += 1638400;   // conv weights fp16
  unsigned short* xhb  = us;  us += 4194304;   // x fp16 -> act fp16 -> qth/qtl -> tailA
  unsigned short* kthb = us;  us += 4194304;   // kth/ktl
  unsigned short* wqh  = us;  us += 32768;
  unsigned short* wkh  = us;  us += 32768;
  unsigned short* wvh  = us;  us += 65536;
  unsigned short* twh  = us;  us += 131072;
  unsigned short* ah   = xhb;
  unsigned short* qth  = xhb;
  unsigned short* qtl  = xhb + 2097152;
  unsigned short* kth  = kthb;
  unsigned short* ktl  = kthb + 2097152;
  unsigned short* vtb  = (unsigned short*)qb;
  unsigned short* tA   = xhb;
  unsigned short* tB   = (unsigned short*)vb;

  // 0. weight preps (fp16)
  hipLaunchKernelGGL(prep_w, dim3(6400), dim3(TPB), 0, stream,
                     w1, b1, w3, b3, w5, b5, wfh, b_eff);
  hipLaunchKernelGGL(prep_wgt, dim3(128), dim3(TPB), 0, stream, wq, wqh, 32768);
  hipLaunchKernelGGL(prep_wgt, dim3(128), dim3(TPB), 0, stream, wk, wkh, 32768);
  hipLaunchKernelGGL(prep_wgt, dim3(256), dim3(TPB), 0, stream, wv, wvh, 65536);
  hipLaunchKernelGGL(prep_wgt, dim3(512), dim3(TPB), 0, stream, tail_w, twh, 131072);
  // 1. x conv (fp16 MFMA single-pass)
  hipLaunchKernelGGL(prep_xh, dim3(2048), dim3(TPB), 0, stream, x, xhb);
  hipLaunchKernelGGL(conv5_mfma, dim3(16, 4, 16), dim3(TPB), 0, stream,
                     xhb, wfh, b_eff, outb);
  // 2. CBAM
  hipLaunchKernelGGL(pool_avgmax, dim3(4096), dim3(TPB), 0, stream, outb, avg, mxp);
  hipLaunchKernelGGL(ca_mlp, dim3(16), dim3(TPB), 0, stream, avg, mxp, ca_w1, ca_w2, cab);
  hipLaunchKernelGGL(mul_ca, dim3(4096), dim3(TPB), 0, stream, outb, cab, cbuf);
  hipLaunchKernelGGL(spatial_pool, dim3(64), dim3(TPB), 0, stream, cbuf, sain);
  hipLaunchKernelGGL(sa_conv, dim3(64), dim3(TPB), 0, stream, sain, sa_w, sab);
  hipLaunchKernelGGL(mul_sa, dim3(4096), dim3(TPB), 0, stream, cbuf, sab);
  // 3. q/k/v GEMMs (fp16 MFMA) on transposed activations
  hipLaunchKernelGGL(prep_xh, dim3(2048), dim3(TPB), 0, stream, outb, ah);
  hipLaunchKernelGGL(gemm_mfma, dim3(16, 2, 16), dim3(TPB), 0, stream,
                     wqh, bq, ah, ah, qb, 128, 256);
  hipLaunchKernelGGL(gemm_mfma, dim3(16, 2, 16), dim3(TPB), 0, stream,
                     wkh, bk, ah, ah, kb, 128, 256);
  hipLaunchKernelGGL(gemm_mfma, dim3(16, 4, 16), dim3(TPB), 0, stream,
                     wvh, bv, ah, ah, vb, 256, 256);
  // 4. attention preps + fused attention (bf16 3-pass, unchanged)
  hipLaunchKernelGGL(sqnorm, dim3(64), dim3(TPB), 0, stream, qb, q2b, 128);
  hipLaunchKernelGGL(sqnorm, dim3(64), dim3(TPB), 0, stream, kb, k2b, 128);
  hipLaunchKernelGGL(xpose_qk, dim3(16, 16), dim3(TPB), 0, stream, qb, qth, qtl);
  hipLaunchKernelGGL(xpose_qk, dim3(16, 16), dim3(TPB), 0, stream, kb, kth, ktl);
  hipLaunchKernelGGL(conv_v, dim3(2048), dim3(TPB), 0, stream, vb, vtb);  // qb dead
  hipLaunchKernelGGL(attn_mfma, dim3(16, 16), dim3(TPB), 0, stream,
                     qth, qtl, kth, ktl, vtb, q2b, k2b, sigma, outb);
  // 5. tail GEMM over concat [cbam_out(cbuf), non_local(outb)]
  hipLaunchKernelGGL(prep_xh, dim3(2048), dim3(TPB), 0, stream, cbuf, tA);  // qth dead
  hipLaunchKernelGGL(prep_xh, dim3(2048), dim3(TPB), 0, stream, outb, tB); // vb dead
  hipLaunchKernelGGL(gemm_mfma, dim3(16, 4, 16), dim3(TPB), 0, stream,
                     twh, tail_b, tA, tB, out_f, 256, 512);
}

// Round 9
// 508.059 us; speedup vs baseline: 1.8395x; 1.0040x over previous
//
#include <hip/hip_runtime.h>
#include <cstddef>

#define TPB 256

typedef __bf16 bf16x8 __attribute__((ext_vector_type(8)));
typedef _Float16 f16x8 __attribute__((ext_vector_type(8)));
typedef float f32x4 __attribute__((ext_vector_type(4)));
typedef unsigned short u16x8 __attribute__((ext_vector_type(8)));

__device__ __forceinline__ unsigned short f2bf(float f) {
  unsigned u = __float_as_uint(f);
  unsigned r = (u + 0x7FFFu + ((u >> 16) & 1u)) >> 16;
  return (unsigned short)r;
}
__device__ __forceinline__ float bf2f(unsigned short h) {
  return __uint_as_float(((unsigned)h) << 16);
}
__device__ __forceinline__ unsigned short f2h(float v) {
  _Float16 h = (_Float16)v;
  unsigned short u;
  __builtin_memcpy(&u, &h, 2);
  return u;
}

// ---------------- P0: merged conv weights -> fp16 [tap][oc][c] ----------------
__global__ __launch_bounds__(TPB) void prep_w(
    const float* __restrict__ w1, const float* __restrict__ b1,
    const float* __restrict__ w3, const float* __restrict__ b3,
    const float* __restrict__ w5, const float* __restrict__ b5,
    unsigned short* __restrict__ wh, float* __restrict__ b_eff) {
  int i = blockIdx.x * TPB + threadIdx.x;  // < 25*65536
  int tap = i >> 16;
  int oc = (i >> 8) & 255;
  int c = i & 255;
  int kh = tap / 5, kw = tap - kh * 5;
  size_t occ = (size_t)((oc << 8) | c);
  float v = w5[occ * 25 + tap];
  if (kh >= 1 && kh <= 3 && kw >= 1 && kw <= 3)
    v += w3[occ * 9 + (kh - 1) * 3 + (kw - 1)];
  if (tap == 12) v += w1[occ];
  wh[i] = f2h(v);
  if (i < 256) b_eff[i] = b1[i] + b3[i] + b5[i];
}

// ---------------- P1: fp32 [b][256][1024] -> fp16 [b][1024][256] ----------------
__global__ __launch_bounds__(TPB) void prep_xh(
    const float* __restrict__ x, unsigned short* __restrict__ xh) {
  int i = blockIdx.x * TPB + threadIdx.x;  // < 16*32*1024
  int b = i >> 15, cg = (i >> 10) & 31, pix = i & 1023;
  u16x8 h8;
#pragma unroll
  for (int j = 0; j < 8; ++j)
    h8[j] = f2h(x[((size_t)(b * 256 + cg * 8 + j)) * 1024 + pix]);
  *(u16x8*)(xh + ((size_t)(b * 1024 + pix)) * 256 + cg * 8) = h8;
}

// ---------------- P2: generic weight fp32 -> fp16 ----------------
__global__ __launch_bounds__(TPB) void prep_wgt(
    const float* __restrict__ w, unsigned short* __restrict__ h, int n) {
  int i = blockIdx.x * TPB + threadIdx.x;
  if (i < n) h[i] = f2h(w[i]);
}

// ---------------- K1: fused 5x5 conv, fp16 MFMA single-pass ----------------
// 1-D grid 1024, XCD-swizzled: xcd=g&7 owns batches {2*xcd, 2*xcd+1}.
// Per batch 64 blocks: 16 h-tiles x 4 oc-tiles. Block = 4 waves.
__global__ __launch_bounds__(TPB) void conv5_mfma(
    const unsigned short* __restrict__ xh, const unsigned short* __restrict__ wh,
    const float* __restrict__ b_eff, float* __restrict__ out) {
  __shared__ unsigned short xs[216 * 32];
  __shared__ unsigned short bs[2][64 * 32];
  const int g = blockIdx.x;
  const int xcd = g & 7, slot = g >> 3;
  const int b = xcd * 2 + (slot >> 6);
  const int sub = slot & 63;
  const int h0 = (sub & 15) * 2;
  const int oc0 = (sub >> 4) * 64;
  const int tid = threadIdx.x;
  const int lane = tid & 63;
  const int w = tid >> 6;
  const int wr = w & 1, wo = w >> 1;
  const int l15 = lane & 15, cg = lane >> 4;

  f32x4 acc[2][2];
#pragma unroll
  for (int mf = 0; mf < 2; ++mf)
#pragma unroll
    for (int nf = 0; nf < 2; ++nf)
#pragma unroll
      for (int r = 0; r < 4; ++r) acc[mf][nf][r] = 0.f;

  const int s_oc = tid >> 2, s_ch = tid & 3;
  const int bso = s_oc * 32 + ((s_ch ^ ((s_oc >> 1) & 3)) * 8);
  const size_t bgbase = (size_t)(oc0 + s_oc) * 256 + s_ch * 8;

  uint4 breg;
  for (int c0 = 0; c0 < 256; c0 += 32) {
    breg = *(const uint4*)(wh + bgbase + c0);  // tap 0, issued before barrier
    __syncthreads();  // prev c0 readers done
    // stage x halo: 216 sites x 4 chunks = 864 tasks
#pragma unroll
    for (int it = 0; it < 4; ++it) {
      int e = tid + it * TPB;
      if (e < 864) {
        int site = e >> 2, ch = e & 3;
        int row = site / 36, col = site - row * 36;
        int ih = h0 + row - 2, iw = col - 2;
        uint4 v = {0u, 0u, 0u, 0u};
        if ((unsigned)ih < 32u && (unsigned)iw < 32u)
          v = *(const uint4*)(xh + ((size_t)(b * 1024 + ih * 32 + iw)) * 256 + c0 + ch * 8);
        *(uint4*)(xs + site * 32 + ((ch ^ ((site >> 1) & 3)) * 8)) = v;
      }
    }
    *(uint4*)(bs[0] + bso) = breg;
    __syncthreads();
    int cur = 0;
#pragma unroll
    for (int kh = 0; kh < 5; ++kh) {
#pragma unroll
      for (int kw = 0; kw < 5; ++kw) {
        const int tap = kh * 5 + kw;
        if (tap < 24)
          breg = *(const uint4*)(wh + (size_t)(tap + 1) * 65536 + bgbase + c0);
        f16x8 A[2], B[2];
#pragma unroll
        for (int mf = 0; mf < 2; ++mf) {
          int as = (wr + kh) * 36 + mf * 16 + l15 + kw;
          A[mf] = *(const f16x8*)(xs + as * 32 + ((cg ^ ((as >> 1) & 3)) * 8));
        }
#pragma unroll
        for (int nf = 0; nf < 2; ++nf) {
          int oc = wo * 32 + nf * 16 + l15;
          B[nf] = *(const f16x8*)(bs[cur] + oc * 32 + ((cg ^ ((oc >> 1) & 3)) * 8));
        }
#pragma unroll
        for (int mf = 0; mf < 2; ++mf)
#pragma unroll
          for (int nf = 0; nf < 2; ++nf)
            acc[mf][nf] = __builtin_amdgcn_mfma_f32_16x16x32_f16(A[mf], B[nf], acc[mf][nf], 0, 0, 0);
        if (tap < 24) {
          *(uint4*)(bs[cur ^ 1] + bso) = breg;
          cur ^= 1;
          __syncthreads();
        }
      }
    }
  }

  // D: row(pixel col)=cg*4+r, col(oc)=l15
#pragma unroll
  for (int mf = 0; mf < 2; ++mf)
#pragma unroll
    for (int nf = 0; nf < 2; ++nf) {
      int oc = oc0 + wo * 32 + nf * 16 + l15;
      float bv = b_eff[oc];
      size_t base = ((size_t)(b * 256 + oc)) * 1024 + (h0 + wr) * 32 + mf * 16 + cg * 4;
      float4 r;
      r.x = acc[mf][nf][0] + bv;
      r.y = acc[mf][nf][1] + bv;
      r.z = acc[mf][nf][2] + bv;
      r.w = acc[mf][nf][3] + bv;
      *(float4*)(out + base) = r;
    }
}

// ---------------- K2: per-(b,c) avg+max pool ----------------
__global__ __launch_bounds__(TPB) void pool_avgmax(
    const float* __restrict__ out, float* __restrict__ avg, float* __restrict__ mx) {
  int bc = blockIdx.x;
  int tid = threadIdx.x;
  const float4 v = ((const float4*)(out + (size_t)bc * 1024))[tid];
  float s = v.x + v.y + v.z + v.w;
  float m = fmaxf(fmaxf(v.x, v.y), fmaxf(v.z, v.w));
#pragma unroll
  for (int off = 1; off < 64; off <<= 1) {
    s += __shfl_xor(s, off);
    m = fmaxf(m, __shfl_xor(m, off));
  }
  __shared__ float ss[4], ms[4];
  if ((tid & 63) == 0) { ss[tid >> 6] = s; ms[tid >> 6] = m; }
  __syncthreads();
  if (tid == 0) {
    s = ss[0] + ss[1] + ss[2] + ss[3];
    m = fmaxf(fmaxf(ms[0], ms[1]), fmaxf(ms[2], ms[3]));
    avg[bc] = s * (1.f / 1024.f);
    mx[bc] = m;
  }
}

// ---------------- K3: channel-attention MLP ----------------
__global__ __launch_bounds__(TPB) void ca_mlp(
    const float* __restrict__ avg, const float* __restrict__ mx,
    const float* __restrict__ w1, const float* __restrict__ w2,
    float* __restrict__ ca) {
  int b = blockIdx.x;
  int t = threadIdx.x;
  __shared__ float av[256], mv[256], h[16];
  av[t] = avg[b * 256 + t];
  mv[t] = mx[b * 256 + t];
  __syncthreads();
  if (t < 16) {
    float ha = 0.f, hm = 0.f;
    for (int c = 0; c < 256; ++c) {
      float wv = w1[t * 256 + c];
      ha += wv * av[c];
      hm += wv * mv[c];
    }
    h[t] = fmaxf(ha, 0.f) + fmaxf(hm, 0.f);
  }
  __syncthreads();
  float s = 0.f;
#pragma unroll
  for (int j = 0; j < 16; ++j) s += w2[t * 16 + j] * h[j];
  ca[b * 256 + t] = 1.f / (1.f + __expf(-s));
}

// ---------------- K4: c = out * ca ----------------
__global__ __launch_bounds__(TPB) void mul_ca(
    const float* __restrict__ out, const float* __restrict__ ca,
    float* __restrict__ cbuf) {
  int i = blockIdx.x * TPB + threadIdx.x;
  float4 v = ((const float4*)out)[i];
  float g = ca[i >> 8];
  v.x *= g; v.y *= g; v.z *= g; v.w *= g;
  ((float4*)cbuf)[i] = v;
}

// ---------------- K5: spatial mean/max over channels ----------------
__global__ __launch_bounds__(TPB) void spatial_pool(
    const float* __restrict__ cbuf, float* __restrict__ sa_in) {
  int i = blockIdx.x * TPB + threadIdx.x;
  int b = i >> 10, pix = i & 1023;
  const float* p = cbuf + (size_t)b * 262144 + pix;
  float s = 0.f, m = -3.4e38f;
  for (int ch = 0; ch < 256; ++ch) {
    float v = p[(size_t)ch * 1024];
    s += v;
    m = fmaxf(m, v);
  }
  sa_in[b * 2048 + pix] = s * (1.f / 256.f);
  sa_in[b * 2048 + 1024 + pix] = m;
}

// ---------------- K6: 7x7 spatial-attn conv + sigmoid ----------------
__global__ __launch_bounds__(TPB) void sa_conv(
    const float* __restrict__ sa_in, const float* __restrict__ sw,
    float* __restrict__ sa) {
  int i = blockIdx.x * TPB + threadIdx.x;
  int b = i >> 10, pix = i & 1023;
  int h = pix >> 5, w = pix & 31;
  float s = 0.f;
#pragma unroll
  for (int ci = 0; ci < 2; ++ci)
    for (int kh = 0; kh < 7; ++kh) {
      int ih = h + kh - 3;
      if ((unsigned)ih >= 32u) continue;
#pragma unroll
      for (int kw = 0; kw < 7; ++kw) {
        int iw = w + kw - 3;
        if ((unsigned)iw >= 32u) continue;
        s += sa_in[b * 2048 + ci * 1024 + ih * 32 + iw] * sw[ci * 49 + kh * 7 + kw];
      }
    }
  sa[i] = 1.f / (1.f + __expf(-s));
}

// ---------------- K7: cbam = c * sa ----------------
__global__ __launch_bounds__(TPB) void mul_sa(
    float* __restrict__ cbuf, const float* __restrict__ sa) {
  int i = blockIdx.x * TPB + threadIdx.x;
  int b = i >> 16;
  float4 g = ((const float4*)(sa + (size_t)b * 1024))[i & 255];
  float4 v = ((float4*)cbuf)[i];
  v.x *= g.x; v.y *= g.y; v.z *= g.z; v.w *= g.w;
  ((float4*)cbuf)[i] = v;
}

// ---------------- fp16 MFMA GEMM 1-pass: Y[b][o][n] = bias[o] + W[o,:]·X[b,n,:] ----------------
__global__ __launch_bounds__(TPB) void gemm_mfma(
    const unsigned short* __restrict__ Wh, const float* __restrict__ bias,
    const unsigned short* __restrict__ Xah, const unsigned short* __restrict__ Xbh,
    float* __restrict__ Y, int O, int K) {
  __shared__ unsigned short Wsm[2][64 * 32], Xsm[2][64 * 32];
  const int tid = threadIdx.x;
  const int n0 = blockIdx.x * 64, o0 = blockIdx.y * 64, b = blockIdx.z;
  const int w = tid >> 6, lane = tid & 63;
  const int l15 = lane & 15, cg = lane >> 4;
  const int s_r = tid >> 2, s_ch = tid & 3;
  const int so = s_r * 32 + ((s_ch ^ ((s_r >> 1) & 3)) * 8);

  f32x4 acc[4];
#pragma unroll
  for (int nf = 0; nf < 4; ++nf)
#pragma unroll
    for (int r = 0; r < 4; ++r) acc[nf][r] = 0.f;

  const int nch = K >> 5;
  uint4 wreg, xreg;
  auto loadc = [&](int kc) {
    int k0 = kc << 5;
    const unsigned short* Xp = Xah;
    int kof = k0;
    if (k0 >= 256) { Xp = Xbh; kof = k0 - 256; }
    wreg = *(const uint4*)(Wh + (size_t)(o0 + s_r) * K + k0 + s_ch * 8);
    xreg = *(const uint4*)(Xp + ((size_t)(b * 1024 + n0 + s_r)) * 256 + kof + s_ch * 8);
  };
  loadc(0);
  *(uint4*)(Wsm[0] + so) = wreg;
  *(uint4*)(Xsm[0] + so) = xreg;
  __syncthreads();
  int cur = 0;
  for (int kc = 0; kc < nch; ++kc) {
    if (kc + 1 < nch) loadc(kc + 1);
    const int orow = w * 16 + l15;
    f16x8 a = *(const f16x8*)(Wsm[cur] + orow * 32 + ((cg ^ ((orow >> 1) & 3)) * 8));
#pragma unroll
    for (int nf = 0; nf < 4; ++nf) {
      int nr = nf * 16 + l15;
      f16x8 xb = *(const f16x8*)(Xsm[cur] + nr * 32 + ((cg ^ ((nr >> 1) & 3)) * 8));
      acc[nf] = __builtin_amdgcn_mfma_f32_16x16x32_f16(a, xb, acc[nf], 0, 0, 0);
    }
    if (kc + 1 < nch) {
      *(uint4*)(Wsm[cur ^ 1] + so) = wreg;
      *(uint4*)(Xsm[cur ^ 1] + so) = xreg;
      cur ^= 1;
      __syncthreads();
    }
  }
  // D: col(n)=l15, row(o)=cg*4+r
#pragma unroll
  for (int r = 0; r < 4; ++r) {
    int o = o0 + w * 16 + cg * 4 + r;
    float bv = bias[o];
    size_t base = ((size_t)b * O + o) * 1024 + n0 + l15;
#pragma unroll
    for (int nf = 0; nf < 4; ++nf) Y[base + nf * 16] = acc[nf][r] + bv;
  }
}

// ---------------- squared norms over channels ----------------
__global__ __launch_bounds__(TPB) void sqnorm(
    const float* __restrict__ src, float* __restrict__ dst, int CC) {
  int i = blockIdx.x * TPB + threadIdx.x;
  int b = i >> 10, n = i & 1023;
  const float* p = src + ((size_t)b * CC) * 1024 + n;
  float s = 0.f;
  for (int c = 0; c < CC; ++c) {
    float v = p[(size_t)c * 1024];
    s = fmaf(v, v, s);
  }
  dst[i] = s;
}

// ---------------- transpose+split: fp32 [b][128][1024] -> bf16 hi/lo [b][1024][128], swizzled ----------------
__global__ __launch_bounds__(TPB) void xpose_qk(
    const float* __restrict__ X, unsigned short* __restrict__ H,
    unsigned short* __restrict__ L) {
  __shared__ float xs[64 * 132];
  const int tid = threadIdx.x;
  const int n0 = blockIdx.x * 64, b = blockIdx.y;
#pragma unroll
  for (int i = 0; i < 8; ++i) {
    int idx = tid + i * TPB;
    int c = idx >> 4, nq = idx & 15;
    float4 f = *(const float4*)&X[((size_t)(b * 128 + c)) * 1024 + n0 + nq * 4];
    xs[(nq * 4 + 0) * 132 + c] = f.x;
    xs[(nq * 4 + 1) * 132 + c] = f.y;
    xs[(nq * 4 + 2) * 132 + c] = f.z;
    xs[(nq * 4 + 3) * 132 + c] = f.w;
  }
  __syncthreads();
#pragma unroll
  for (int i = 0; i < 4; ++i) {
    int idx = tid + i * TPB;
    int n = idx >> 4, oct = idx & 15;
    u16x8 h8, l8;
#pragma unroll
    for (int j = 0; j < 8; ++j) {
      float v = xs[n * 132 + oct * 8 + j];
      unsigned short h = f2bf(v);
      h8[j] = h;
      l8[j] = f2bf(v - bf2f(h));
    }
    int byteoff = (oct * 16) ^ ((n & 7) << 4);
    size_t rowbase = ((size_t)(b * 1024 + n0 + n)) * 256;  // bytes
    *(u16x8*)((char*)H + rowbase + byteoff) = h8;
    *(u16x8*)((char*)L + rowbase + byteoff) = l8;
  }
}

// ---------------- V convert: fp32 [b][256][1024] -> bf16 same layout, swizzled ----------------
__global__ __launch_bounds__(TPB) void conv_v(
    const float* __restrict__ V, unsigned short* __restrict__ O) {
  int id = blockIdx.x * TPB + threadIdx.x;
  int j = id & 127, c = (id >> 7) & 255, b = id >> 15;
  const float* p = V + ((size_t)(b * 256 + c)) * 1024 + j * 8;
  float4 f0 = *(const float4*)p;
  float4 f1 = *(const float4*)(p + 4);
  u16x8 h8;
  h8[0] = f2bf(f0.x); h8[1] = f2bf(f0.y); h8[2] = f2bf(f0.z); h8[3] = f2bf(f0.w);
  h8[4] = f2bf(f1.x); h8[5] = f2bf(f1.y); h8[6] = f2bf(f1.z); h8[7] = f2bf(f1.w);
  size_t rowbase = ((size_t)(b * 256 + c)) * 2048;  // bytes
  int byteoff = (j * 16) ^ ((c & 7) << 4);
  *(u16x8*)((char*)O + rowbase + byteoff) = h8;
}

// ---------------- fused non-local attention via bf16 MFMA (3-pass QK^T) ----------------
// 1-D grid 256, XCD-swizzled: xcd=g&7 owns batches {2*xcd, 2*xcd+1} (16 n-tile
// blocks each) -> per-batch K/V/Q (~1.5MB) stays resident in that XCD's 4MB L2.
__global__ __launch_bounds__(TPB, 2) void attn_mfma(
    const unsigned short* __restrict__ qth, const unsigned short* __restrict__ qtl,
    const unsigned short* __restrict__ kth, const unsigned short* __restrict__ ktl,
    const unsigned short* __restrict__ vt,
    const float* __restrict__ q2g, const float* __restrict__ k2g,
    const float* __restrict__ sigp, float* __restrict__ out) {
  __shared__ unsigned short ksh[64 * 128], ksl[64 * 128];
  __shared__ unsigned short vsm[256 * 64];
  __shared__ unsigned short pls[4][16 * 64];
  const int g = blockIdx.x;
  const int xcd = g & 7, slot = g >> 3;
  const int b = xcd * 2 + (slot >> 4);
  const int n0 = (slot & 15) * 64;
  const int tid = threadIdx.x;
  const int w = tid >> 6, lane = tid & 63;
  const int l15 = lane & 15, cg = lane >> 4;
  const float sg = *sigp;
  const float inv2s = 0.5f / (sg * sg);

  const int nq = n0 + w * 16 + l15;
  bf16x8 qh[4], ql[4];
  {
    const char* qrh = (const char*)qth + ((size_t)(b * 1024 + nq)) * 256;
    const char* qrl = (const char*)qtl + ((size_t)(b * 1024 + nq)) * 256;
    int sw = (nq & 7) << 4;
#pragma unroll
    for (int kc = 0; kc < 4; ++kc) {
      int o = (kc * 64 + cg * 16) ^ sw;
      qh[kc] = *(const bf16x8*)(qrh + o);
      ql[kc] = *(const bf16x8*)(qrl + o);
    }
  }
  float q2r[4];
#pragma unroll
  for (int r = 0; r < 4; ++r) q2r[r] = q2g[b * 1024 + n0 + w * 16 + cg * 4 + r];
  float dsum[4] = {0.f, 0.f, 0.f, 0.f};
  f32x4 acc[16];
#pragma unroll
  for (int cf = 0; cf < 16; ++cf)
#pragma unroll
    for (int r = 0; r < 4; ++r) acc[cf][r] = 0.f;

  const unsigned short* kh_g = kth + ((size_t)b * 1024) * 128;
  const unsigned short* kl_g = ktl + ((size_t)b * 1024) * 128;
  const unsigned short* v_g = vt + ((size_t)b * 256) * 1024;

  uint4 stg[16];
  auto load_tile = [&](int m0) {
#pragma unroll
    for (int i = 0; i < 4; ++i) {
      int off = (w + 4 * i) * 512 + lane * 8;
      stg[i] = *(const uint4*)(kh_g + (size_t)m0 * 128 + off);
      stg[4 + i] = *(const uint4*)(kl_g + (size_t)m0 * 128 + off);
    }
#pragma unroll
    for (int i = 0; i < 8; ++i) {
      int ch = w + 4 * i;
      int cp = ch * 8 + (lane >> 3);
      stg[8 + i] = *(const uint4*)(v_g + (size_t)cp * 1024 + m0 + (lane & 7) * 8);
    }
  };
  auto write_tile = [&]() {
#pragma unroll
    for (int i = 0; i < 4; ++i) {
      int off = (w + 4 * i) * 512 + lane * 8;
      *(uint4*)(ksh + off) = stg[i];
      *(uint4*)(ksl + off) = stg[4 + i];
    }
#pragma unroll
    for (int i = 0; i < 8; ++i) {
      int off = (w + 4 * i) * 512 + lane * 8;
      *(uint4*)(vsm + off) = stg[8 + i];
    }
  };

  load_tile(0);
  write_tile();
  __syncthreads();

  char* pmy = (char*)pls[w];
  const int psw = (l15 & 7) << 4;

  for (int t = 0; t < 16; ++t) {
    const int m0 = t * 64;
    float k2r[4];
#pragma unroll
    for (int mf = 0; mf < 4; ++mf) k2r[mf] = k2g[b * 1024 + m0 + mf * 16 + l15];
    if (t < 15) load_tile(m0 + 64);

    f32x4 s[4];
#pragma unroll
    for (int mf = 0; mf < 4; ++mf)
#pragma unroll
      for (int r = 0; r < 4; ++r) s[mf][r] = 0.f;
#pragma unroll
    for (int mf = 0; mf < 4; ++mf) {
      const char* krh = (const char*)ksh + (mf * 16 + l15) * 256;
      const char* krl = (const char*)ksl + (mf * 16 + l15) * 256;
      int sw = ((mf * 16 + l15) & 7) << 4;
#pragma unroll
      for (int kc = 0; kc < 4; ++kc) {
        int o = (kc * 64 + cg * 16) ^ sw;
        bf16x8 kh8 = *(const bf16x8*)(krh + o);
        bf16x8 kl8 = *(const bf16x8*)(krl + o);
        s[mf] = __builtin_amdgcn_mfma_f32_16x16x32_bf16(qh[kc], kh8, s[mf], 0, 0, 0);
        s[mf] = __builtin_amdgcn_mfma_f32_16x16x32_bf16(qh[kc], kl8, s[mf], 0, 0, 0);
        s[mf] = __builtin_amdgcn_mfma_f32_16x16x32_bf16(ql[kc], kh8, s[mf], 0, 0, 0);
      }
    }
#pragma unroll
    for (int mf = 0; mf < 4; ++mf) {
      int mloc = mf * 16 + l15;
#pragma unroll
      for (int r = 0; r < 4; ++r) {
        float d = q2r[r] + k2r[mf] - 2.f * s[mf][r];
        float sim = __expf(-d * inv2s);
        float p = __expf(sim);
        dsum[r] += p;
        int nl = cg * 4 + r;
        *(unsigned short*)(pmy + nl * 128 + ((mloc * 2) ^ ((nl & 7) << 4))) = f2bf(p);
      }
    }
    bf16x8 pa[2];
#pragma unroll
    for (int kc2 = 0; kc2 < 2; ++kc2)
      pa[kc2] = *(const bf16x8*)(pmy + l15 * 128 + ((kc2 * 64 + cg * 16) ^ psw));
#pragma unroll
    for (int cf = 0; cf < 16; ++cf) {
      int cp = cf * 16 + l15;
      const char* vrow = (const char*)vsm + cp * 128;
      int sw = (cp & 7) << 4;
#pragma unroll
      for (int kc2 = 0; kc2 < 2; ++kc2) {
        bf16x8 vb8 = *(const bf16x8*)(vrow + ((kc2 * 64 + cg * 16) ^ sw));
        acc[cf] = __builtin_amdgcn_mfma_f32_16x16x32_bf16(pa[kc2], vb8, acc[cf], 0, 0, 0);
      }
    }
    __syncthreads();
    if (t < 15) write_tile();
    __syncthreads();
  }

#pragma unroll
  for (int r = 0; r < 4; ++r) {
    dsum[r] += __shfl_xor(dsum[r], 1);
    dsum[r] += __shfl_xor(dsum[r], 2);
    dsum[r] += __shfl_xor(dsum[r], 4);
    dsum[r] += __shfl_xor(dsum[r], 8);
  }
#pragma unroll
  for (int r = 0; r < 4; ++r) {
    float rv = 1.f / dsum[r];
    size_t base = (size_t)b * 262144 + (size_t)(n0 + w * 16 + cg * 4 + r) * 256;
#pragma unroll
    for (int cf = 0; cf < 16; ++cf) {
      size_t idx = base + cf * 16 + l15;
      out[idx] += acc[cf][r] * rv;
    }
  }
}

// ---------------- launcher ----------------
extern "C" void kernel_launch(void* const* d_in, const int* in_sizes, int n_in,
                              void* d_out, int out_size, void* d_ws, size_t ws_size,
                              hipStream_t stream) {
  (void)in_sizes; (void)n_in; (void)out_size; (void)ws_size;
  const float* x      = (const float*)d_in[0];
  const float* w1     = (const float*)d_in[1];
  const float* b1     = (const float*)d_in[2];
  const float* w3     = (const float*)d_in[3];
  const float* b3     = (const float*)d_in[4];
  const float* w5     = (const float*)d_in[5];
  const float* b5     = (const float*)d_in[6];
  const float* wq     = (const float*)d_in[7];
  const float* bq     = (const float*)d_in[8];
  const float* wk     = (const float*)d_in[9];
  const float* bk     = (const float*)d_in[10];
  const float* wv     = (const float*)d_in[11];
  const float* bv     = (const float*)d_in[12];
  const float* sigma  = (const float*)d_in[13];
  const float* ca_w1  = (const float*)d_in[14];
  const float* ca_w2  = (const float*)d_in[15];
  const float* sa_w   = (const float*)d_in[16];
  const float* tail_w = (const float*)d_in[17];
  const float* tail_b = (const float*)d_in[18];
  float* out_f = (float*)d_out;

  float* ws = (float*)d_ws;
  float* outb  = ws;  ws += 4194304;
  float* cbuf  = ws;  ws += 4194304;
  float* qb    = ws;  ws += 2097152;   // fp32 q; later vtb (bf16 V)
  float* kb    = ws;  ws += 2097152;
  float* vb    = ws;  ws += 4194304;   // fp32 v; later tail-part2 fp16
  float* b_eff = ws;  ws += 256;
  float* avg   = ws;  ws += 4096;
  float* mxp   = ws;  ws += 4096;
  float* cab   = ws;  ws += 4096;
  float* sain  = ws;  ws += 32768;
  float* sab   = ws;  ws += 16384;
  float* q2b   = ws;  ws += 16384;
  float* k2b   = ws;  ws += 16384;
  unsigned short* us = (unsigned short*)ws;
  unsigned short* wfh  = us;  us += 1638400;   // conv weights fp16
  unsigned short* xhb  = us;  us += 4194304;   // x fp16 -> act fp16 -> qth/qtl -> tailA
  unsigned short* kthb = us;  us += 4194304;   // kth/ktl
  unsigned short* wqh  = us;  us += 32768;
  unsigned short* wkh  = us;  us += 32768;
  unsigned short* wvh  = us;  us += 65536;
  unsigned short* twh  = us;  us += 131072;
  unsigned short* ah   = xhb;
  unsigned short* qth  = xhb;
  unsigned short* qtl  = xhb + 2097152;
  unsigned short* kth  = kthb;
  unsigned short* ktl  = kthb + 2097152;
  unsigned short* vtb  = (unsigned short*)qb;
  unsigned short* tA   = xhb;
  unsigned short* tB   = (unsigned short*)vb;

  // 0. weight preps (fp16)
  hipLaunchKernelGGL(prep_w, dim3(6400), dim3(TPB), 0, stream,
                     w1, b1, w3, b3, w5, b5, wfh, b_eff);
  hipLaunchKernelGGL(prep_wgt, dim3(128), dim3(TPB), 0, stream, wq, wqh, 32768);
  hipLaunchKernelGGL(prep_wgt, dim3(128), dim3(TPB), 0, stream, wk, wkh, 32768);
  hipLaunchKernelGGL(prep_wgt, dim3(256), dim3(TPB), 0, stream, wv, wvh, 65536);
  hipLaunchKernelGGL(prep_wgt, dim3(512), dim3(TPB), 0, stream, tail_w, twh, 131072);
  // 1. x conv (fp16 MFMA single-pass, XCD-swizzled grid)
  hipLaunchKernelGGL(prep_xh, dim3(2048), dim3(TPB), 0, stream, x, xhb);
  hipLaunchKernelGGL(conv5_mfma, dim3(1024), dim3(TPB), 0, stream,
                     xhb, wfh, b_eff, outb);
  // 2. CBAM
  hipLaunchKernelGGL(pool_avgmax, dim3(4096), dim3(TPB), 0, stream, outb, avg, mxp);
  hipLaunchKernelGGL(ca_mlp, dim3(16), dim3(TPB), 0, stream, avg, mxp, ca_w1, ca_w2, cab);
  hipLaunchKernelGGL(mul_ca, dim3(4096), dim3(TPB), 0, stream, outb, cab, cbuf);
  hipLaunchKernelGGL(spatial_pool, dim3(64), dim3(TPB), 0, stream, cbuf, sain);
  hipLaunchKernelGGL(sa_conv, dim3(64), dim3(TPB), 0, stream, sain, sa_w, sab);
  hipLaunchKernelGGL(mul_sa, dim3(4096), dim3(TPB), 0, stream, cbuf, sab);
  // 3. q/k/v GEMMs (fp16 MFMA) on transposed activations
  hipLaunchKernelGGL(prep_xh, dim3(2048), dim3(TPB), 0, stream, outb, ah);
  hipLaunchKernelGGL(gemm_mfma, dim3(16, 2, 16), dim3(TPB), 0, stream,
                     wqh, bq, ah, ah, qb, 128, 256);
  hipLaunchKernelGGL(gemm_mfma, dim3(16, 2, 16), dim3(TPB), 0, stream,
                     wkh, bk, ah, ah, kb, 128, 256);
  hipLaunchKernelGGL(gemm_mfma, dim3(16, 4, 16), dim3(TPB), 0, stream,
                     wvh, bv, ah, ah, vb, 256, 256);
  // 4. attention preps + fused attention (bf16 3-pass, XCD-swizzled grid)
  hipLaunchKernelGGL(sqnorm, dim3(64), dim3(TPB), 0, stream, qb, q2b, 128);
  hipLaunchKernelGGL(sqnorm, dim3(64), dim3(TPB), 0, stream, kb, k2b, 128);
  hipLaunchKernelGGL(xpose_qk, dim3(16, 16), dim3(TPB), 0, stream, qb, qth, qtl);
  hipLaunchKernelGGL(xpose_qk, dim3(16, 16), dim3(TPB), 0, stream, kb, kth, ktl);
  hipLaunchKernelGGL(conv_v, dim3(2048), dim3(TPB), 0, stream, vb, vtb);  // qb dead
  hipLaunchKernelGGL(attn_mfma, dim3(256), dim3(TPB), 0, stream,
                     qth, qtl, kth, ktl, vtb, q2b, k2b, sigma, outb);
  // 5. tail GEMM over concat [cbam_out(cbuf), non_local(outb)]
  hipLaunchKernelGGL(prep_xh, dim3(2048), dim3(TPB), 0, stream, cbuf, tA);  // qth dead
  hipLaunchKernelGGL(prep_xh, dim3(2048), dim3(TPB), 0, stream, outb, tB); // vb dead
  hipLaunchKernelGGL(gemm_mfma, dim3(16, 4, 16), dim3(TPB), 0, stream,
                     twh, tail_b, tA, tB, out_f, 256, 512);
}

// Round 10
// 444.943 us; speedup vs baseline: 2.1005x; 1.1419x over previous
//
#include <hip/hip_runtime.h>
#include <cstddef>

#define TPB 256

typedef __bf16 bf16x8 __attribute__((ext_vector_type(8)));
typedef _Float16 f16x8 __attribute__((ext_vector_type(8)));
typedef float f32x4 __attribute__((ext_vector_type(4)));
typedef unsigned short u16x8 __attribute__((ext_vector_type(8)));

__device__ __forceinline__ unsigned short f2bf(float f) {
  unsigned u = __float_as_uint(f);
  unsigned r = (u + 0x7FFFu + ((u >> 16) & 1u)) >> 16;
  return (unsigned short)r;
}
__device__ __forceinline__ float bf2f(unsigned short h) {
  return __uint_as_float(((unsigned)h) << 16);
}
__device__ __forceinline__ unsigned short f2h(float v) {
  _Float16 h = (_Float16)v;
  unsigned short u;
  __builtin_memcpy(&u, &h, 2);
  return u;
}
// async global->LDS, 16B per lane; LDS dest = wave-uniform base + lane*16
__device__ __forceinline__ void gload_lds16(const void* g, void* l) {
  __builtin_amdgcn_global_load_lds(
      (const __attribute__((address_space(1))) unsigned int*)g,
      (__attribute__((address_space(3))) unsigned int*)l, 16, 0, 0);
}

// ---------------- P0: merged conv weights -> fp16 [tap][oc][c] ----------------
__global__ __launch_bounds__(TPB) void prep_w(
    const float* __restrict__ w1, const float* __restrict__ b1,
    const float* __restrict__ w3, const float* __restrict__ b3,
    const float* __restrict__ w5, const float* __restrict__ b5,
    unsigned short* __restrict__ wh, float* __restrict__ b_eff) {
  int i = blockIdx.x * TPB + threadIdx.x;  // < 25*65536
  int tap = i >> 16;
  int oc = (i >> 8) & 255;
  int c = i & 255;
  int kh = tap / 5, kw = tap - kh * 5;
  size_t occ = (size_t)((oc << 8) | c);
  float v = w5[occ * 25 + tap];
  if (kh >= 1 && kh <= 3 && kw >= 1 && kw <= 3)
    v += w3[occ * 9 + (kh - 1) * 3 + (kw - 1)];
  if (tap == 12) v += w1[occ];
  wh[i] = f2h(v);
  if (i < 256) b_eff[i] = b1[i] + b3[i] + b5[i];
}

// ---------------- P1: fp32 [b][256][1024] -> fp16 [b][1024][256] ----------------
__global__ __launch_bounds__(TPB) void prep_xh(
    const float* __restrict__ x, unsigned short* __restrict__ xh) {
  int i = blockIdx.x * TPB + threadIdx.x;  // < 16*32*1024
  int b = i >> 15, cg = (i >> 10) & 31, pix = i & 1023;
  u16x8 h8;
#pragma unroll
  for (int j = 0; j < 8; ++j)
    h8[j] = f2h(x[((size_t)(b * 256 + cg * 8 + j)) * 1024 + pix]);
  *(u16x8*)(xh + ((size_t)(b * 1024 + pix)) * 256 + cg * 8) = h8;
}

// ---------------- P2: generic weight fp32 -> fp16 ----------------
__global__ __launch_bounds__(TPB) void prep_wgt(
    const float* __restrict__ w, unsigned short* __restrict__ h, int n) {
  int i = blockIdx.x * TPB + threadIdx.x;
  if (i < n) h[i] = f2h(w[i]);
}

// ---------------- K1: fused 5x5 conv, fp16 MFMA single-pass ----------------
__global__ __launch_bounds__(TPB) void conv5_mfma(
    const unsigned short* __restrict__ xh, const unsigned short* __restrict__ wh,
    const float* __restrict__ b_eff, float* __restrict__ out) {
  __shared__ unsigned short xs[216 * 32];
  __shared__ unsigned short bs[2][64 * 32];
  const int g = blockIdx.x;
  const int xcd = g & 7, slot = g >> 3;
  const int b = xcd * 2 + (slot >> 6);
  const int sub = slot & 63;
  const int h0 = (sub & 15) * 2;
  const int oc0 = (sub >> 4) * 64;
  const int tid = threadIdx.x;
  const int lane = tid & 63;
  const int w = tid >> 6;
  const int wr = w & 1, wo = w >> 1;
  const int l15 = lane & 15, cg = lane >> 4;

  f32x4 acc[2][2];
#pragma unroll
  for (int mf = 0; mf < 2; ++mf)
#pragma unroll
    for (int nf = 0; nf < 2; ++nf)
#pragma unroll
      for (int r = 0; r < 4; ++r) acc[mf][nf][r] = 0.f;

  const int s_oc = tid >> 2, s_ch = tid & 3;
  const int bso = s_oc * 32 + ((s_ch ^ ((s_oc >> 1) & 3)) * 8);
  const size_t bgbase = (size_t)(oc0 + s_oc) * 256 + s_ch * 8;

  uint4 breg;
  for (int c0 = 0; c0 < 256; c0 += 32) {
    breg = *(const uint4*)(wh + bgbase + c0);
    __syncthreads();
#pragma unroll
    for (int it = 0; it < 4; ++it) {
      int e = tid + it * TPB;
      if (e < 864) {
        int site = e >> 2, ch = e & 3;
        int row = site / 36, col = site - row * 36;
        int ih = h0 + row - 2, iw = col - 2;
        uint4 v = {0u, 0u, 0u, 0u};
        if ((unsigned)ih < 32u && (unsigned)iw < 32u)
          v = *(const uint4*)(xh + ((size_t)(b * 1024 + ih * 32 + iw)) * 256 + c0 + ch * 8);
        *(uint4*)(xs + site * 32 + ((ch ^ ((site >> 1) & 3)) * 8)) = v;
      }
    }
    *(uint4*)(bs[0] + bso) = breg;
    __syncthreads();
    int cur = 0;
#pragma unroll
    for (int kh = 0; kh < 5; ++kh) {
#pragma unroll
      for (int kw = 0; kw < 5; ++kw) {
        const int tap = kh * 5 + kw;
        if (tap < 24)
          breg = *(const uint4*)(wh + (size_t)(tap + 1) * 65536 + bgbase + c0);
        f16x8 A[2], B[2];
#pragma unroll
        for (int mf = 0; mf < 2; ++mf) {
          int as = (wr + kh) * 36 + mf * 16 + l15 + kw;
          A[mf] = *(const f16x8*)(xs + as * 32 + ((cg ^ ((as >> 1) & 3)) * 8));
        }
#pragma unroll
        for (int nf = 0; nf < 2; ++nf) {
          int oc = wo * 32 + nf * 16 + l15;
          B[nf] = *(const f16x8*)(bs[cur] + oc * 32 + ((cg ^ ((oc >> 1) & 3)) * 8));
        }
#pragma unroll
        for (int mf = 0; mf < 2; ++mf)
#pragma unroll
          for (int nf = 0; nf < 2; ++nf)
            acc[mf][nf] = __builtin_amdgcn_mfma_f32_16x16x32_f16(A[mf], B[nf], acc[mf][nf], 0, 0, 0);
        if (tap < 24) {
          *(uint4*)(bs[cur ^ 1] + bso) = breg;
          cur ^= 1;
          __syncthreads();
        }
      }
    }
  }

#pragma unroll
  for (int mf = 0; mf < 2; ++mf)
#pragma unroll
    for (int nf = 0; nf < 2; ++nf) {
      int oc = oc0 + wo * 32 + nf * 16 + l15;
      float bv = b_eff[oc];
      size_t base = ((size_t)(b * 256 + oc)) * 1024 + (h0 + wr) * 32 + mf * 16 + cg * 4;
      float4 r;
      r.x = acc[mf][nf][0] + bv;
      r.y = acc[mf][nf][1] + bv;
      r.z = acc[mf][nf][2] + bv;
      r.w = acc[mf][nf][3] + bv;
      *(float4*)(out + base) = r;
    }
}

// ---------------- K2: per-(b,c) avg+max pool ----------------
__global__ __launch_bounds__(TPB) void pool_avgmax(
    const float* __restrict__ out, float* __restrict__ avg, float* __restrict__ mx) {
  int bc = blockIdx.x;
  int tid = threadIdx.x;
  const float4 v = ((const float4*)(out + (size_t)bc * 1024))[tid];
  float s = v.x + v.y + v.z + v.w;
  float m = fmaxf(fmaxf(v.x, v.y), fmaxf(v.z, v.w));
#pragma unroll
  for (int off = 1; off < 64; off <<= 1) {
    s += __shfl_xor(s, off);
    m = fmaxf(m, __shfl_xor(m, off));
  }
  __shared__ float ss[4], ms[4];
  if ((tid & 63) == 0) { ss[tid >> 6] = s; ms[tid >> 6] = m; }
  __syncthreads();
  if (tid == 0) {
    s = ss[0] + ss[1] + ss[2] + ss[3];
    m = fmaxf(fmaxf(ms[0], ms[1]), fmaxf(ms[2], ms[3]));
    avg[bc] = s * (1.f / 1024.f);
    mx[bc] = m;
  }
}

// ---------------- K3: channel-attention MLP ----------------
__global__ __launch_bounds__(TPB) void ca_mlp(
    const float* __restrict__ avg, const float* __restrict__ mx,
    const float* __restrict__ w1, const float* __restrict__ w2,
    float* __restrict__ ca) {
  int b = blockIdx.x;
  int t = threadIdx.x;
  __shared__ float av[256], mv[256], h[16];
  av[t] = avg[b * 256 + t];
  mv[t] = mx[b * 256 + t];
  __syncthreads();
  if (t < 16) {
    float ha = 0.f, hm = 0.f;
    for (int c = 0; c < 256; ++c) {
      float wv = w1[t * 256 + c];
      ha += wv * av[c];
      hm += wv * mv[c];
    }
    h[t] = fmaxf(ha, 0.f) + fmaxf(hm, 0.f);
  }
  __syncthreads();
  float s = 0.f;
#pragma unroll
  for (int j = 0; j < 16; ++j) s += w2[t * 16 + j] * h[j];
  ca[b * 256 + t] = 1.f / (1.f + __expf(-s));
}

// ---------------- K4: c = out * ca ----------------
__global__ __launch_bounds__(TPB) void mul_ca(
    const float* __restrict__ out, const float* __restrict__ ca,
    float* __restrict__ cbuf) {
  int i = blockIdx.x * TPB + threadIdx.x;
  float4 v = ((const float4*)out)[i];
  float g = ca[i >> 8];
  v.x *= g; v.y *= g; v.z *= g; v.w *= g;
  ((float4*)cbuf)[i] = v;
}

// ---------------- K5: spatial mean/max over channels ----------------
__global__ __launch_bounds__(TPB) void spatial_pool(
    const float* __restrict__ cbuf, float* __restrict__ sa_in) {
  int i = blockIdx.x * TPB + threadIdx.x;
  int b = i >> 10, pix = i & 1023;
  const float* p = cbuf + (size_t)b * 262144 + pix;
  float s = 0.f, m = -3.4e38f;
  for (int ch = 0; ch < 256; ++ch) {
    float v = p[(size_t)ch * 1024];
    s += v;
    m = fmaxf(m, v);
  }
  sa_in[b * 2048 + pix] = s * (1.f / 256.f);
  sa_in[b * 2048 + 1024 + pix] = m;
}

// ---------------- K6: 7x7 spatial-attn conv + sigmoid ----------------
__global__ __launch_bounds__(TPB) void sa_conv(
    const float* __restrict__ sa_in, const float* __restrict__ sw,
    float* __restrict__ sa) {
  int i = blockIdx.x * TPB + threadIdx.x;
  int b = i >> 10, pix = i & 1023;
  int h = pix >> 5, w = pix & 31;
  float s = 0.f;
#pragma unroll
  for (int ci = 0; ci < 2; ++ci)
    for (int kh = 0; kh < 7; ++kh) {
      int ih = h + kh - 3;
      if ((unsigned)ih >= 32u) continue;
#pragma unroll
      for (int kw = 0; kw < 7; ++kw) {
        int iw = w + kw - 3;
        if ((unsigned)iw >= 32u) continue;
        s += sa_in[b * 2048 + ci * 1024 + ih * 32 + iw] * sw[ci * 49 + kh * 7 + kw];
      }
    }
  sa[i] = 1.f / (1.f + __expf(-s));
}

// ---------------- K7: cbam = c * sa ----------------
__global__ __launch_bounds__(TPB) void mul_sa(
    float* __restrict__ cbuf, const float* __restrict__ sa) {
  int i = blockIdx.x * TPB + threadIdx.x;
  int b = i >> 16;
  float4 g = ((const float4*)(sa + (size_t)b * 1024))[i & 255];
  float4 v = ((float4*)cbuf)[i];
  v.x *= g.x; v.y *= g.y; v.z *= g.z; v.w *= g.w;
  ((float4*)cbuf)[i] = v;
}

// ---------------- fp16 MFMA GEMM 1-pass ----------------
__global__ __launch_bounds__(TPB) void gemm_mfma(
    const unsigned short* __restrict__ Wh, const float* __restrict__ bias,
    const unsigned short* __restrict__ Xah, const unsigned short* __restrict__ Xbh,
    float* __restrict__ Y, int O, int K) {
  __shared__ unsigned short Wsm[2][64 * 32], Xsm[2][64 * 32];
  const int tid = threadIdx.x;
  const int n0 = blockIdx.x * 64, o0 = blockIdx.y * 64, b = blockIdx.z;
  const int w = tid >> 6, lane = tid & 63;
  const int l15 = lane & 15, cg = lane >> 4;
  const int s_r = tid >> 2, s_ch = tid & 3;
  const int so = s_r * 32 + ((s_ch ^ ((s_r >> 1) & 3)) * 8);

  f32x4 acc[4];
#pragma unroll
  for (int nf = 0; nf < 4; ++nf)
#pragma unroll
    for (int r = 0; r < 4; ++r) acc[nf][r] = 0.f;

  const int nch = K >> 5;
  uint4 wreg, xreg;
  auto loadc = [&](int kc) {
    int k0 = kc << 5;
    const unsigned short* Xp = Xah;
    int kof = k0;
    if (k0 >= 256) { Xp = Xbh; kof = k0 - 256; }
    wreg = *(const uint4*)(Wh + (size_t)(o0 + s_r) * K + k0 + s_ch * 8);
    xreg = *(const uint4*)(Xp + ((size_t)(b * 1024 + n0 + s_r)) * 256 + kof + s_ch * 8);
  };
  loadc(0);
  *(uint4*)(Wsm[0] + so) = wreg;
  *(uint4*)(Xsm[0] + so) = xreg;
  __syncthreads();
  int cur = 0;
  for (int kc = 0; kc < nch; ++kc) {
    if (kc + 1 < nch) loadc(kc + 1);
    const int orow = w * 16 + l15;
    f16x8 a = *(const f16x8*)(Wsm[cur] + orow * 32 + ((cg ^ ((orow >> 1) & 3)) * 8));
#pragma unroll
    for (int nf = 0; nf < 4; ++nf) {
      int nr = nf * 16 + l15;
      f16x8 xb = *(const f16x8*)(Xsm[cur] + nr * 32 + ((cg ^ ((nr >> 1) & 3)) * 8));
      acc[nf] = __builtin_amdgcn_mfma_f32_16x16x32_f16(a, xb, acc[nf], 0, 0, 0);
    }
    if (kc + 1 < nch) {
      *(uint4*)(Wsm[cur ^ 1] + so) = wreg;
      *(uint4*)(Xsm[cur ^ 1] + so) = xreg;
      cur ^= 1;
      __syncthreads();
    }
  }
#pragma unroll
  for (int r = 0; r < 4; ++r) {
    int o = o0 + w * 16 + cg * 4 + r;
    float bv = bias[o];
    size_t base = ((size_t)b * O + o) * 1024 + n0 + l15;
#pragma unroll
    for (int nf = 0; nf < 4; ++nf) Y[base + nf * 16] = acc[nf][r] + bv;
  }
}

// ---------------- squared norms over channels ----------------
__global__ __launch_bounds__(TPB) void sqnorm(
    const float* __restrict__ src, float* __restrict__ dst, int CC) {
  int i = blockIdx.x * TPB + threadIdx.x;
  int b = i >> 10, n = i & 1023;
  const float* p = src + ((size_t)b * CC) * 1024 + n;
  float s = 0.f;
  for (int c = 0; c < CC; ++c) {
    float v = p[(size_t)c * 1024];
    s = fmaf(v, v, s);
  }
  dst[i] = s;
}

// ---------------- transpose+split: fp32 [b][128][1024] -> bf16 hi/lo [b][1024][128], swizzled ----------------
__global__ __launch_bounds__(TPB) void xpose_qk(
    const float* __restrict__ X, unsigned short* __restrict__ H,
    unsigned short* __restrict__ L) {
  __shared__ float xs[64 * 132];
  const int tid = threadIdx.x;
  const int n0 = blockIdx.x * 64, b = blockIdx.y;
#pragma unroll
  for (int i = 0; i < 8; ++i) {
    int idx = tid + i * TPB;
    int c = idx >> 4, nq = idx & 15;
    float4 f = *(const float4*)&X[((size_t)(b * 128 + c)) * 1024 + n0 + nq * 4];
    xs[(nq * 4 + 0) * 132 + c] = f.x;
    xs[(nq * 4 + 1) * 132 + c] = f.y;
    xs[(nq * 4 + 2) * 132 + c] = f.z;
    xs[(nq * 4 + 3) * 132 + c] = f.w;
  }
  __syncthreads();
#pragma unroll
  for (int i = 0; i < 4; ++i) {
    int idx = tid + i * TPB;
    int n = idx >> 4, oct = idx & 15;
    u16x8 h8, l8;
#pragma unroll
    for (int j = 0; j < 8; ++j) {
      float v = xs[n * 132 + oct * 8 + j];
      unsigned short h = f2bf(v);
      h8[j] = h;
      l8[j] = f2bf(v - bf2f(h));
    }
    int byteoff = (oct * 16) ^ ((n & 7) << 4);
    size_t rowbase = ((size_t)(b * 1024 + n0 + n)) * 256;  // bytes
    *(u16x8*)((char*)H + rowbase + byteoff) = h8;
    *(u16x8*)((char*)L + rowbase + byteoff) = l8;
  }
}

// ---------------- V convert: fp32 [b][256][1024] -> bf16 same layout, swizzled ----------------
__global__ __launch_bounds__(TPB) void conv_v(
    const float* __restrict__ V, unsigned short* __restrict__ O) {
  int id = blockIdx.x * TPB + threadIdx.x;
  int j = id & 127, c = (id >> 7) & 255, b = id >> 15;
  const float* p = V + ((size_t)(b * 256 + c)) * 1024 + j * 8;
  float4 f0 = *(const float4*)p;
  float4 f1 = *(const float4*)(p + 4);
  u16x8 h8;
  h8[0] = f2bf(f0.x); h8[1] = f2bf(f0.y); h8[2] = f2bf(f0.z); h8[3] = f2bf(f0.w);
  h8[4] = f2bf(f1.x); h8[5] = f2bf(f1.y); h8[6] = f2bf(f1.z); h8[7] = f2bf(f1.w);
  size_t rowbase = ((size_t)(b * 256 + c)) * 2048;  // bytes
  int byteoff = (j * 16) ^ ((c & 7) << 4);
  *(u16x8*)((char*)O + rowbase + byteoff) = h8;
}

// ---------------- fused non-local attention via bf16 MFMA (3-pass QK^T) ----------------
// grid 256 XCD-swizzled; double-buffered LDS K/V via global_load_lds (no reg
// staging -> no scratch spills); 1 barrier/tile (drains vmcnt for prefetch).
__global__ __launch_bounds__(TPB) void attn_mfma(
    const unsigned short* __restrict__ qth, const unsigned short* __restrict__ qtl,
    const unsigned short* __restrict__ kth, const unsigned short* __restrict__ ktl,
    const unsigned short* __restrict__ vt,
    const float* __restrict__ q2g, const float* __restrict__ k2g,
    const float* __restrict__ sigp, float* __restrict__ out) {
  __shared__ unsigned short ksh[2][64 * 128];
  __shared__ unsigned short ksl[2][64 * 128];
  __shared__ unsigned short vsm[2][256 * 64];
  __shared__ unsigned short pls[4][16 * 64];
  const int g = blockIdx.x;
  const int xcd = g & 7, slot = g >> 3;
  const int b = xcd * 2 + (slot >> 4);
  const int n0 = (slot & 15) * 64;
  const int tid = threadIdx.x;
  const int w = tid >> 6, lane = tid & 63;
  const int l15 = lane & 15, cg = lane >> 4;
  const float sg = *sigp;
  const float inv2s = 0.5f / (sg * sg);

  const int nq = n0 + w * 16 + l15;
  bf16x8 qh[4], ql[4];
  {
    const char* qrh = (const char*)qth + ((size_t)(b * 1024 + nq)) * 256;
    const char* qrl = (const char*)qtl + ((size_t)(b * 1024 + nq)) * 256;
    int sw = (nq & 7) << 4;
#pragma unroll
    for (int kc = 0; kc < 4; ++kc) {
      int o = (kc * 64 + cg * 16) ^ sw;
      qh[kc] = *(const bf16x8*)(qrh + o);
      ql[kc] = *(const bf16x8*)(qrl + o);
    }
  }
  float q2r[4];
#pragma unroll
  for (int r = 0; r < 4; ++r) q2r[r] = q2g[b * 1024 + n0 + w * 16 + cg * 4 + r];
  float dsum[4] = {0.f, 0.f, 0.f, 0.f};
  f32x4 acc[16];
#pragma unroll
  for (int cf = 0; cf < 16; ++cf)
#pragma unroll
    for (int r = 0; r < 4; ++r) acc[cf][r] = 0.f;

  const unsigned short* kh_g = kth + ((size_t)b * 1024) * 128;
  const unsigned short* kl_g = ktl + ((size_t)b * 1024) * 128;
  const unsigned short* v_g = vt + ((size_t)b * 256) * 1024;

  // async stage of one 64-key tile into LDS buffer `buf` (per-lane global
  // addr, linear wave-uniform LDS dest + lane*16B, pre-swizzled in global)
  auto stage = [&](int m0, int buf) {
#pragma unroll
    for (int i = 0; i < 4; ++i) {
      int row = w + 4 * i;  // 2-row chunks of 512 shorts
      int goff = row * 512 + lane * 8;
      gload_lds16(kh_g + (size_t)m0 * 128 + goff, &ksh[buf][row * 512]);
      gload_lds16(kl_g + (size_t)m0 * 128 + goff, &ksl[buf][row * 512]);
    }
#pragma unroll
    for (int i = 0; i < 8; ++i) {
      int ch = w + 4 * i;
      int cp = ch * 8 + (lane >> 3);
      gload_lds16(v_g + (size_t)cp * 1024 + m0 + (lane & 7) * 8, &vsm[buf][ch * 512]);
    }
  };

  stage(0, 0);
  __syncthreads();

  char* pmy = (char*)pls[w];
  const int psw = (l15 & 7) << 4;

  for (int t = 0; t < 16; ++t) {
    const int m0 = t * 64;
    const int cur = t & 1;
    if (t < 15) stage(m0 + 64, cur ^ 1);  // async prefetch, drained by barrier
    float k2r[4];
#pragma unroll
    for (int mf = 0; mf < 4; ++mf) k2r[mf] = k2g[b * 1024 + m0 + mf * 16 + l15];

    f32x4 s[4];
#pragma unroll
    for (int mf = 0; mf < 4; ++mf)
#pragma unroll
      for (int r = 0; r < 4; ++r) s[mf][r] = 0.f;
#pragma unroll
    for (int mf = 0; mf < 4; ++mf) {
      const char* krh = (const char*)ksh[cur] + (mf * 16 + l15) * 256;
      const char* krl = (const char*)ksl[cur] + (mf * 16 + l15) * 256;
      int sw = ((mf * 16 + l15) & 7) << 4;
#pragma unroll
      for (int kc = 0; kc < 4; ++kc) {
        int o = (kc * 64 + cg * 16) ^ sw;
        bf16x8 kh8 = *(const bf16x8*)(krh + o);
        bf16x8 kl8 = *(const bf16x8*)(krl + o);
        s[mf] = __builtin_amdgcn_mfma_f32_16x16x32_bf16(qh[kc], kh8, s[mf], 0, 0, 0);
        s[mf] = __builtin_amdgcn_mfma_f32_16x16x32_bf16(qh[kc], kl8, s[mf], 0, 0, 0);
        s[mf] = __builtin_amdgcn_mfma_f32_16x16x32_bf16(ql[kc], kh8, s[mf], 0, 0, 0);
      }
    }
#pragma unroll
    for (int mf = 0; mf < 4; ++mf) {
      int mloc = mf * 16 + l15;
#pragma unroll
      for (int r = 0; r < 4; ++r) {
        float d = q2r[r] + k2r[mf] - 2.f * s[mf][r];
        float sim = __expf(-d * inv2s);
        float p = __expf(sim);
        dsum[r] += p;
        int nl = cg * 4 + r;
        *(unsigned short*)(pmy + nl * 128 + ((mloc * 2) ^ ((nl & 7) << 4))) = f2bf(p);
      }
    }
    bf16x8 pa[2];
#pragma unroll
    for (int kc2 = 0; kc2 < 2; ++kc2)
      pa[kc2] = *(const bf16x8*)(pmy + l15 * 128 + ((kc2 * 64 + cg * 16) ^ psw));
#pragma unroll
    for (int cf = 0; cf < 16; ++cf) {
      int cp = cf * 16 + l15;
      const char* vrow = (const char*)vsm[cur] + cp * 128;
      int sw = (cp & 7) << 4;
#pragma unroll
      for (int kc2 = 0; kc2 < 2; ++kc2) {
        bf16x8 vb8 = *(const bf16x8*)(vrow + ((kc2 * 64 + cg * 16) ^ sw));
        acc[cf] = __builtin_amdgcn_mfma_f32_16x16x32_bf16(pa[kc2], vb8, acc[cf], 0, 0, 0);
      }
    }
    __syncthreads();  // waits vmcnt(0): prefetch for t+1 complete; P reuse safe
  }

#pragma unroll
  for (int r = 0; r < 4; ++r) {
    dsum[r] += __shfl_xor(dsum[r], 1);
    dsum[r] += __shfl_xor(dsum[r], 2);
    dsum[r] += __shfl_xor(dsum[r], 4);
    dsum[r] += __shfl_xor(dsum[r], 8);
  }
#pragma unroll
  for (int r = 0; r < 4; ++r) {
    float rv = 1.f / dsum[r];
    size_t base = (size_t)b * 262144 + (size_t)(n0 + w * 16 + cg * 4 + r) * 256;
#pragma unroll
    for (int cf = 0; cf < 16; ++cf) {
      size_t idx = base + cf * 16 + l15;
      out[idx] += acc[cf][r] * rv;
    }
  }
}

// ---------------- launcher ----------------
extern "C" void kernel_launch(void* const* d_in, const int* in_sizes, int n_in,
                              void* d_out, int out_size, void* d_ws, size_t ws_size,
                              hipStream_t stream) {
  (void)in_sizes; (void)n_in; (void)out_size; (void)ws_size;
  const float* x      = (const float*)d_in[0];
  const float* w1     = (const float*)d_in[1];
  const float* b1     = (const float*)d_in[2];
  const float* w3     = (const float*)d_in[3];
  const float* b3     = (const float*)d_in[4];
  const float* w5     = (const float*)d_in[5];
  const float* b5     = (const float*)d_in[6];
  const float* wq     = (const float*)d_in[7];
  const float* bq     = (const float*)d_in[8];
  const float* wk     = (const float*)d_in[9];
  const float* bk     = (const float*)d_in[10];
  const float* wv     = (const float*)d_in[11];
  const float* bv     = (const float*)d_in[12];
  const float* sigma  = (const float*)d_in[13];
  const float* ca_w1  = (const float*)d_in[14];
  const float* ca_w2  = (const float*)d_in[15];
  const float* sa_w   = (const float*)d_in[16];
  const float* tail_w = (const float*)d_in[17];
  const float* tail_b = (const float*)d_in[18];
  float* out_f = (float*)d_out;

  float* ws = (float*)d_ws;
  float* outb  = ws;  ws += 4194304;
  float* cbuf  = ws;  ws += 4194304;
  float* qb    = ws;  ws += 2097152;   // fp32 q; later vtb (bf16 V)
  float* kb    = ws;  ws += 2097152;
  float* vb    = ws;  ws += 4194304;   // fp32 v; later tail-part2 fp16
  float* b_eff = ws;  ws += 256;
  float* avg   = ws;  ws += 4096;
  float* mxp   = ws;  ws += 4096;
  float* cab   = ws;  ws += 4096;
  float* sain  = ws;  ws += 32768;
  float* sab   = ws;  ws += 16384;
  float* q2b   = ws;  ws += 16384;
  float* k2b   = ws;  ws += 16384;
  unsigned short* us = (unsigned short*)ws;
  unsigned short* wfh  = us;  us += 1638400;   // conv weights fp16
  unsigned short* xhb  = us;  us += 4194304;   // x fp16 -> act fp16 -> qth/qtl -> tailA
  unsigned short* kthb = us;  us += 4194304;   // kth/ktl
  unsigned short* wqh  = us;  us += 32768;
  unsigned short* wkh  = us;  us += 32768;
  unsigned short* wvh  = us;  us += 65536;
  unsigned short* twh  = us;  us += 131072;
  unsigned short* ah   = xhb;
  unsigned short* qth  = xhb;
  unsigned short* qtl  = xhb + 2097152;
  unsigned short* kth  = kthb;
  unsigned short* ktl  = kthb + 2097152;
  unsigned short* vtb  = (unsigned short*)qb;
  unsigned short* tA   = xhb;
  unsigned short* tB   = (unsigned short*)vb;

  // 0. weight preps (fp16)
  hipLaunchKernelGGL(prep_w, dim3(6400), dim3(TPB), 0, stream,
                     w1, b1, w3, b3, w5, b5, wfh, b_eff);
  hipLaunchKernelGGL(prep_wgt, dim3(128), dim3(TPB), 0, stream, wq, wqh, 32768);
  hipLaunchKernelGGL(prep_wgt, dim3(128), dim3(TPB), 0, stream, wk, wkh, 32768);
  hipLaunchKernelGGL(prep_wgt, dim3(256), dim3(TPB), 0, stream, wv, wvh, 65536);
  hipLaunchKernelGGL(prep_wgt, dim3(512), dim3(TPB), 0, stream, tail_w, twh, 131072);
  // 1. x conv (fp16 MFMA single-pass, XCD-swizzled grid)
  hipLaunchKernelGGL(prep_xh, dim3(2048), dim3(TPB), 0, stream, x, xhb);
  hipLaunchKernelGGL(conv5_mfma, dim3(1024), dim3(TPB), 0, stream,
                     xhb, wfh, b_eff, outb);
  // 2. CBAM
  hipLaunchKernelGGL(pool_avgmax, dim3(4096), dim3(TPB), 0, stream, outb, avg, mxp);
  hipLaunchKernelGGL(ca_mlp, dim3(16), dim3(TPB), 0, stream, avg, mxp, ca_w1, ca_w2, cab);
  hipLaunchKernelGGL(mul_ca, dim3(4096), dim3(TPB), 0, stream, outb, cab, cbuf);
  hipLaunchKernelGGL(spatial_pool, dim3(64), dim3(TPB), 0, stream, cbuf, sain);
  hipLaunchKernelGGL(sa_conv, dim3(64), dim3(TPB), 0, stream, sain, sa_w, sab);
  hipLaunchKernelGGL(mul_sa, dim3(4096), dim3(TPB), 0, stream, cbuf, sab);
  // 3. q/k/v GEMMs (fp16 MFMA) on transposed activations
  hipLaunchKernelGGL(prep_xh, dim3(2048), dim3(TPB), 0, stream, outb, ah);
  hipLaunchKernelGGL(gemm_mfma, dim3(16, 2, 16), dim3(TPB), 0, stream,
                     wqh, bq, ah, ah, qb, 128, 256);
  hipLaunchKernelGGL(gemm_mfma, dim3(16, 2, 16), dim3(TPB), 0, stream,
                     wkh, bk, ah, ah, kb, 128, 256);
  hipLaunchKernelGGL(gemm_mfma, dim3(16, 4, 16), dim3(TPB), 0, stream,
                     wvh, bv, ah, ah, vb, 256, 256);
  // 4. attention preps + fused attention (bf16 3-pass, XCD-swizzled grid)
  hipLaunchKernelGGL(sqnorm, dim3(64), dim3(TPB), 0, stream, qb, q2b, 128);
  hipLaunchKernelGGL(sqnorm, dim3(64), dim3(TPB), 0, stream, kb, k2b, 128);
  hipLaunchKernelGGL(xpose_qk, dim3(16, 16), dim3(TPB), 0, stream, qb, qth, qtl);
  hipLaunchKernelGGL(xpose_qk, dim3(16, 16), dim3(TPB), 0, stream, kb, kth, ktl);
  hipLaunchKernelGGL(conv_v, dim3(2048), dim3(TPB), 0, stream, vb, vtb);  // qb dead
  hipLaunchKernelGGL(attn_mfma, dim3(256), dim3(TPB), 0, stream,
                     qth, qtl, kth, ktl, vtb, q2b, k2b, sigma, outb);
  // 5. tail GEMM over concat [cbam_out(cbuf), non_local(outb)]
  hipLaunchKernelGGL(prep_xh, dim3(2048), dim3(TPB), 0, stream, cbuf, tA);  // qth dead
  hipLaunchKernelGGL(prep_xh, dim3(2048), dim3(TPB), 0, stream, outb, tB); // vb dead
  hipLaunchKernelGGL(gemm_mfma, dim3(16, 4, 16), dim3(TPB), 0, stream,
                     twh, tail_b, tA, tB, out_f, 256, 512);
}